// Round 1
// baseline (258.425 us; speedup 1.0000x reference)
//
#include <hip/hip_runtime.h>

#define CIN 128
#define COUT 256
#define IH 96
#define IW 96
#define NB 8
#define HW (IH*IW)          // 9216
#define NPIX (NB*HW)        // 73728
#define AST 136             // LDS A-tile row stride (shorts)
#define BLK_PER_IMG (HW/64) // 144

typedef __attribute__((ext_vector_type(8))) short short8;
typedef __attribute__((ext_vector_type(4))) float floatx4;

static __device__ __forceinline__ short f2bf(float f) {
  unsigned int u = __builtin_bit_cast(unsigned int, f);
  u = u + 0x7fffu + ((u >> 16) & 1u);
  return (short)(u >> 16);
}
static __device__ __forceinline__ float bf2f(short s) {
  unsigned int u = ((unsigned int)(unsigned short)s) << 16;
  return __builtin_bit_cast(float, u);
}

struct Corner {
  float w00, w01, w10, w11;
  const short *r00, *r01, *r10, *r11;
};

// bilinear corner weights (validity & mask folded) + NHWC row pointers
static __device__ __forceinline__ Corner corner_setup(float py, float px, float mk,
                                                      const short* xtb, int choff) {
  Corner c;
  float y0f = floorf(py), x0f = floorf(px);
  float wy1 = py - y0f, wx1 = px - x0f;
  float wy0 = 1.f - wy1, wx0 = 1.f - wx1;
  bool vy0 = (y0f >= 0.f) && (y0f <= (float)(IH - 1));
  bool vy1 = (y0f + 1.f >= 0.f) && (y0f + 1.f <= (float)(IH - 1));
  bool vx0 = (x0f >= 0.f) && (x0f <= (float)(IW - 1));
  bool vx1 = (x0f + 1.f >= 0.f) && (x0f + 1.f <= (float)(IW - 1));
  int iy0 = min(max((int)y0f, 0), IH - 1);
  int iy1 = min(max((int)y0f + 1, 0), IH - 1);
  int ix0 = min(max((int)x0f, 0), IW - 1);
  int ix1 = min(max((int)x0f + 1, 0), IW - 1);
  c.w00 = wy0 * wx0 * mk * ((vy0 && vx0) ? 1.f : 0.f);
  c.w01 = wy0 * wx1 * mk * ((vy0 && vx1) ? 1.f : 0.f);
  c.w10 = wy1 * wx0 * mk * ((vy1 && vx0) ? 1.f : 0.f);
  c.w11 = wy1 * wx1 * mk * ((vy1 && vx1) ? 1.f : 0.f);
  c.r00 = xtb + (size_t)(iy0 * IW + ix0) * 128 + choff;
  c.r01 = xtb + (size_t)(iy0 * IW + ix1) * 128 + choff;
  c.r10 = xtb + (size_t)(iy1 * IW + ix0) * 128 + choff;
  c.r11 = xtb + (size_t)(iy1 * IW + ix1) * 128 + choff;
  return c;
}

static __device__ __forceinline__ short8 interp8(short8 s00, short8 s01,
                                                 short8 s10, short8 s11,
                                                 const Corner& c) {
  short8 o;
  #pragma unroll
  for (int j = 0; j < 8; ++j) {
    float v = c.w00 * bf2f(s00[j]) + c.w01 * bf2f(s01[j])
            + c.w10 * bf2f(s10[j]) + c.w11 * bf2f(s11[j]);
    o[j] = f2bf(v);
  }
  return o;
}

// ---------------------------------------------------------------------------
// Kernel 0: pack weights into FRAGMENT-LINEAR bf16 streams (unchanged).
// ---------------------------------------------------------------------------
__global__ void prep_weights(const float* __restrict__ weight,
                             const float* __restrict__ offset_w,
                             const float* __restrict__ mask_w,
                             short* __restrict__ Bt2f,
                             short* __restrict__ Bt1f) {
  int idx = blockIdx.x * 256 + threadIdx.x;
  const int n2 = 9 * 4 * 16 * 512;          // 294912
  if (idx < n2) {
    int e = idx & 7, lane = (idx >> 3) & 63;
    int g = idx >> 9;
    int nl = g & 15, kq = (g >> 4) & 3, tap = g >> 6;
    int o = nl * 16 + (lane & 15);
    int c = kq * 32 + (lane >> 4) * 8 + e;
    Bt2f[idx] = f2bf(weight[(o * CIN + c) * 9 + tap]);
  } else {
    int j = idx - n2;
    if (j < 9 * 4 * 2 * 512) {              // 36864
      int e = j & 7, lane = (j >> 3) & 63;
      int g = j >> 9;
      int nl = g & 1, kq = (g >> 1) & 3, tap = g >> 3;
      int n = nl * 16 + (lane & 15);
      int c = kq * 32 + (lane >> 4) * 8 + e;
      float v = 0.f;
      if (n < 27)
        v = (n < 18) ? offset_w[(n * CIN + c) * 9 + tap]
                     : mask_w[((n - 18) * CIN + c) * 9 + tap];
      Bt1f[j] = f2bf(v);
    }
  }
}

// ---------------------------------------------------------------------------
// Kernel 0b: transpose x NCHW fp32 -> NHWC bf16 (unchanged).
// ---------------------------------------------------------------------------
__global__ __launch_bounds__(256, 8)
void transpose_x(const float* __restrict__ x, short* __restrict__ xt) {
  __shared__ short tile[64 * 130];
  const int tid = threadIdx.x;
  const int lane = tid & 63;
  const int wv = tid >> 6;
  const int p0 = blockIdx.x * 64;
  const int b = p0 / HW;
  const int hw0 = p0 % HW;
  const float* xb = x + (size_t)b * CIN * HW + hw0;

  #pragma unroll
  for (int i = 0; i < 32; ++i) {
    int c = wv + i * 4;
    tile[lane * 130 + c] = f2bf(xb[(size_t)c * HW + lane]);
  }
  __syncthreads();

  unsigned int* dst = (unsigned int*)(xt + ((size_t)b * HW + hw0) * 128);
  #pragma unroll
  for (int i = 0; i < 16; ++i) {
    int idx = i * 256 + tid;
    int px = idx >> 6, cw = idx & 63;
    unsigned int lo = (unsigned short)tile[px * 130 + 2 * cw];
    unsigned int hi = (unsigned short)tile[px * 130 + 2 * cw + 1];
    dst[idx] = lo | (hi << 16);
  }
}

// ---------------------------------------------------------------------------
// Kernel 1: offset+mask conv.  Per tap: issue ALL 12 loads (4 A + 8 B) with
// 12-deep ILP, one wait, 8 MFMAs.  launch_bounds(256,4) so VGPRs allow the
// in-flight loads (R3's (256,8)/VGPR=32 serialized every load -> 144 us).
// ---------------------------------------------------------------------------
__global__ __launch_bounds__(256, 4)
void offmask_kernel(const short* __restrict__ xt,
                    const short* __restrict__ Bt1f,
                    const float* __restrict__ offset_b,
                    const float* __restrict__ mask_b,
                    float* __restrict__ pmt) {
  const int tid  = threadIdx.x;
  const int lane = tid & 63;
  const int wv   = tid >> 6;
  const int q    = lane >> 4;
  const int m    = lane & 15;
  const int blk  = blockIdx.x;
  const int l    = (blk & 7) * BLK_PER_IMG + (blk >> 3);
  const int p0   = l * 64;
  const int b    = p0 / HW;
  const int p    = p0 + wv * 16 + m;
  const int hw   = p % HW;
  const int h    = hw / IW, w_ = hw % IW;
  const short* xtb = xt + (size_t)b * HW * 128;

  floatx4 acc0 = (floatx4){0.f, 0.f, 0.f, 0.f};
  floatx4 acc1 = (floatx4){0.f, 0.f, 0.f, 0.f};

  for (int tap = 0; tap < 9; ++tap) {
    const int kh = tap / 3, kw = tap % 3;
    const int iy = h + kh - 1, ix = w_ + kw - 1;
    const bool vald = (iy >= 0 && iy < IH && ix >= 0 && ix < IW);
    const size_t pbase = vald ? (size_t)(iy * IW + ix) * 128 : 0;

    short8 a[4], bb0[4], bb1[4];
    #pragma unroll
    for (int kq = 0; kq < 4; ++kq)
      a[kq] = *(const short8*)(xtb + pbase + kq * 32 + q * 8);
    #pragma unroll
    for (int kq = 0; kq < 4; ++kq) {
      bb0[kq] = *(const short8*)(Bt1f + (size_t)((tap * 4 + kq) * 2 + 0) * 512 + lane * 8);
      bb1[kq] = *(const short8*)(Bt1f + (size_t)((tap * 4 + kq) * 2 + 1) * 512 + lane * 8);
    }
    #pragma unroll
    for (int kq = 0; kq < 4; ++kq) {
      short8 av = a[kq];
      if (!vald) av = (short8){0, 0, 0, 0, 0, 0, 0, 0};
      acc0 = __builtin_amdgcn_mfma_f32_16x16x32_bf16(av, bb0[kq], acc0, 0, 0, 0);
      acc1 = __builtin_amdgcn_mfma_f32_16x16x32_bf16(av, bb1[kq], acc1, 0, 0, 0);
    }
  }

  #pragma unroll
  for (int nl = 0; nl < 2; ++nl) {
    floatx4 ac = nl ? acc1 : acc0;
    int ch = nl * 16 + m;
    if (ch < 18) {
      int tap = ch >> 1, plane = ch & 1;
      float cb = offset_b[ch];
      #pragma unroll
      for (int r = 0; r < 4; ++r) {
        int pp = p0 + wv * 16 + q * 4 + r;
        int hwp = pp % HW;
        float base = plane ? (float)(hwp % IW + tap % 3 - 1)
                           : (float)(hwp / IW + tap / 3 - 1);
        pmt[(size_t)(plane * 9 + tap) * NPIX + pp] = ac[r] + cb + base;
      }
    } else if (ch < 27) {
      int tap = ch - 18;
      float cb = mask_b[tap];
      #pragma unroll
      for (int r = 0; r < 4; ++r) {
        int pp = p0 + wv * 16 + q * 4 + r;
        float v = ac[r] + cb;
        pmt[(size_t)(18 + tap) * NPIX + pp] = 1.f / (1.f + expf(-v));
      }
    }
  }
}

// ---------------------------------------------------------------------------
// Kernel 2: fused sampling + deformable GEMM, chunk-level software pipeline.
//  Per tap t: B-frags loaded per kq (first, so their waits don't drain the
//  gathers), next-tap gather chunk kq issued, 16 MFMAs, then interp+LDS-write
//  of the PREVIOUS chunk (full kq-step of latency for each gather; interp
//  VALU co-issues with the MFMA pipe).  pmt prefetched one tap ahead.
//  LDS chunks XOR-swizzled by (px&3) -> staging writes & frag reads 2-way max.
// ---------------------------------------------------------------------------
__global__ __launch_bounds__(256, 3)
void deform_main(const short* __restrict__ xt,
                 const short* __restrict__ Bt2f,
                 const float* __restrict__ pmt,
                 const float* __restrict__ bias,
                 float* __restrict__ out) {
  __shared__ short Ald[2][64 * AST];        // 34816 B

  const int tid  = threadIdx.x;
  const int lane = tid & 63;
  const int wv   = tid >> 6;
  const int q    = lane >> 4;
  const int m    = lane & 15;
  const int blk  = blockIdx.x;
  const int l    = (blk & 7) * BLK_PER_IMG + (blk >> 3);
  const int p0   = l * 64;
  const int b    = p0 / HW;
  const short* xtb = xt + (size_t)b * HW * 128;

  const int spx   = lane;                   // pixel this thread stages
  const int p_s   = p0 + spx;
  const int choff = wv * 32;                // channel window staged (shorts)
  const int wsw   = spx & 3;                // write-side XOR key
  const int rsw   = m & 3;                  // read-side XOR key
  short* const myrow0 = &Ald[0][spx * AST];
  short* const myrow1 = &Ald[1][spx * AST];

  floatx4 acc[4][4];
  #pragma unroll
  for (int i = 0; i < 4; ++i)
    #pragma unroll
    for (int j = 0; j < 4; ++j) acc[i][j] = (floatx4){0.f, 0.f, 0.f, 0.f};

  // ---- stage tap 0 ----
  {
    float py = pmt[p_s];
    float px = pmt[(size_t)9 * NPIX + p_s];
    float mk = pmt[(size_t)18 * NPIX + p_s];
    Corner c = corner_setup(py, px, mk, xtb, choff);
    #pragma unroll
    for (int i = 0; i < 4; ++i) {
      short8 s00 = *(const short8*)(c.r00 + i * 8);
      short8 s01 = *(const short8*)(c.r01 + i * 8);
      short8 s10 = *(const short8*)(c.r10 + i * 8);
      short8 s11 = *(const short8*)(c.r11 + i * 8);
      *(short8*)(myrow0 + ((wv * 4 + i) ^ wsw) * 8) = interp8(s00, s01, s10, s11, c);
    }
  }
  // preload pmt for tap 1
  float pyN = pmt[(size_t)1 * NPIX + p_s];
  float pxN = pmt[(size_t)10 * NPIX + p_s];
  float mkN = pmt[(size_t)19 * NPIX + p_s];
  __syncthreads();

  for (int tap = 0; tap < 9; ++tap) {
    const short* bufr = Ald[tap & 1];
    short* const roww = (tap & 1) ? myrow0 : myrow1;
    const bool nxt = (tap < 8);

    Corner c;
    if (nxt) c = corner_setup(pyN, pxN, mkN, xtb, choff);
    if (tap < 7) {
      pyN = pmt[(size_t)(tap + 2) * NPIX + p_s];
      pxN = pmt[(size_t)(tap + 11) * NPIX + p_s];
      mkN = pmt[(size_t)(tap + 20) * NPIX + p_s];
    }

    short8 gp00, gp01, gp10, gp11;          // previous chunk's gathers
    #pragma unroll
    for (int kq = 0; kq < 4; ++kq) {
      // B-frags first (their waitcnt must not drain this kq's gathers)
      short8 bf[4];
      #pragma unroll
      for (int nl = 0; nl < 4; ++nl)
        bf[nl] = *(const short8*)(Bt2f + (size_t)((tap * 4 + kq) * 16 + wv * 4 + nl) * 512 + lane * 8);
      // next-tap gather, chunk kq
      short8 g00, g01, g10, g11;
      if (nxt) {
        g00 = *(const short8*)(c.r00 + kq * 8);
        g01 = *(const short8*)(c.r01 + kq * 8);
        g10 = *(const short8*)(c.r10 + kq * 8);
        g11 = *(const short8*)(c.r11 + kq * 8);
      }
      // A-frags from LDS + MFMAs
      short8 af[4];
      #pragma unroll
      for (int mt = 0; mt < 4; ++mt)
        af[mt] = *(const short8*)(bufr + (mt * 16 + m) * AST + ((kq * 4 + q) ^ rsw) * 8);
      #pragma unroll
      for (int mt = 0; mt < 4; ++mt)
        #pragma unroll
        for (int nl = 0; nl < 4; ++nl)
          acc[mt][nl] = __builtin_amdgcn_mfma_f32_16x16x32_bf16(af[mt], bf[nl], acc[mt][nl], 0, 0, 0);
      // interp + write PREVIOUS chunk (its gathers have had a full kq-step)
      if (nxt && kq > 0)
        *(short8*)(roww + ((wv * 4 + kq - 1) ^ wsw) * 8) = interp8(gp00, gp01, gp10, gp11, c);
      gp00 = g00; gp01 = g01; gp10 = g10; gp11 = g11;
    }
    if (nxt) {
      *(short8*)(roww + ((wv * 4 + 3) ^ wsw) * 8) = interp8(gp00, gp01, gp10, gp11, c);
      __syncthreads();
    }
  }

  // ---- epilogue: direct stores.  D: row=q*4+r -> px mt*16+q*4+r, col=m ----
  const int hw0 = p0 % HW;
  #pragma unroll
  for (int nl = 0; nl < 4; ++nl) {
    const int o = wv * 64 + nl * 16 + m;
    const float bs = bias[o];
    float* op = out + (size_t)(b * COUT + o) * HW + hw0;
    #pragma unroll
    for (int mt = 0; mt < 4; ++mt) {
      floatx4 v = acc[mt][nl];
      v[0] += bs; v[1] += bs; v[2] += bs; v[3] += bs;
      *(floatx4*)(op + mt * 16 + q * 4) = v;
    }
  }
}

// ---------------------------------------------------------------------------
extern "C" void kernel_launch(void* const* d_in, const int* in_sizes, int n_in,
                              void* d_out, int out_size, void* d_ws, size_t ws_size,
                              hipStream_t stream) {
  const float* x        = (const float*)d_in[0];
  const float* offset_w = (const float*)d_in[1];
  const float* offset_b = (const float*)d_in[2];
  const float* mask_w   = (const float*)d_in[3];
  const float* mask_b   = (const float*)d_in[4];
  const float* weight   = (const float*)d_in[5];
  const float* bias     = (const float*)d_in[6];
  float* out = (float*)d_out;

  char* ws = (char*)d_ws;
  const size_t XT_BYTES  = (size_t)NPIX * 128 * 2;        // 18,874,368
  const size_t PMT_BYTES = (size_t)27 * NPIX * 4;         //  7,962,624
  const size_t BT2_BYTES = (size_t)9 * 4 * 16 * 512 * 2;  //    589,824
  short* xtp  = (short*)ws;
  float* pmt  = (float*)(ws + XT_BYTES);
  short* Bt2f = (short*)(ws + XT_BYTES + PMT_BYTES);
  short* Bt1f = (short*)(ws + XT_BYTES + PMT_BYTES + BT2_BYTES);

  prep_weights<<<dim3(1296), dim3(256), 0, stream>>>(weight, offset_w, mask_w, Bt2f, Bt1f);
  transpose_x<<<dim3(NPIX / 64), dim3(256), 0, stream>>>(x, xtp);
  offmask_kernel<<<dim3(NPIX / 64), dim3(256), 0, stream>>>(xtp, Bt1f, offset_b, mask_b, pmt);
  deform_main<<<dim3(NPIX / 64), dim3(256), 0, stream>>>(xtp, Bt2f, pmt, bias, out);
}

// Round 2
// 257.319 us; speedup vs baseline: 1.0043x; 1.0043x over previous
//
#include <hip/hip_runtime.h>

#define CIN 128
#define COUT 256
#define IH 96
#define IW 96
#define NB 8
#define HW (IH*IW)          // 9216
#define NPIX (NB*HW)        // 73728
#define AST 136             // LDS A-tile row stride (shorts), 17 x 16B chunks
#define BLK_PER_IMG (HW/64) // 144

typedef __attribute__((ext_vector_type(8))) short short8;
typedef __attribute__((ext_vector_type(4))) float floatx4;

static __device__ __forceinline__ short f2bf(float f) {
  unsigned int u = __builtin_bit_cast(unsigned int, f);
  u = u + 0x7fffu + ((u >> 16) & 1u);
  return (short)(u >> 16);
}
static __device__ __forceinline__ float bf2f(short s) {
  unsigned int u = ((unsigned int)(unsigned short)s) << 16;
  return __builtin_bit_cast(float, u);
}

struct Corner {
  float w00, w01, w10, w11;
  const short *r00, *r01, *r10, *r11;
};

// bilinear corner weights (validity & mask folded) + NHWC row pointers
static __device__ __forceinline__ Corner corner_setup(float py, float px, float mk,
                                                      const short* xtb, int choff) {
  Corner c;
  float y0f = floorf(py), x0f = floorf(px);
  float wy1 = py - y0f, wx1 = px - x0f;
  float wy0 = 1.f - wy1, wx0 = 1.f - wx1;
  bool vy0 = (y0f >= 0.f) && (y0f <= (float)(IH - 1));
  bool vy1 = (y0f + 1.f >= 0.f) && (y0f + 1.f <= (float)(IH - 1));
  bool vx0 = (x0f >= 0.f) && (x0f <= (float)(IW - 1));
  bool vx1 = (x0f + 1.f >= 0.f) && (x0f + 1.f <= (float)(IW - 1));
  int iy0 = min(max((int)y0f, 0), IH - 1);
  int iy1 = min(max((int)y0f + 1, 0), IH - 1);
  int ix0 = min(max((int)x0f, 0), IW - 1);
  int ix1 = min(max((int)x0f + 1, 0), IW - 1);
  c.w00 = wy0 * wx0 * mk * ((vy0 && vx0) ? 1.f : 0.f);
  c.w01 = wy0 * wx1 * mk * ((vy0 && vx1) ? 1.f : 0.f);
  c.w10 = wy1 * wx0 * mk * ((vy1 && vx0) ? 1.f : 0.f);
  c.w11 = wy1 * wx1 * mk * ((vy1 && vx1) ? 1.f : 0.f);
  c.r00 = xtb + (size_t)(iy0 * IW + ix0) * 128 + choff;
  c.r01 = xtb + (size_t)(iy0 * IW + ix1) * 128 + choff;
  c.r10 = xtb + (size_t)(iy1 * IW + ix0) * 128 + choff;
  c.r11 = xtb + (size_t)(iy1 * IW + ix1) * 128 + choff;
  return c;
}

static __device__ __forceinline__ short8 interp8(short8 s00, short8 s01,
                                                 short8 s10, short8 s11,
                                                 const Corner& c) {
  short8 o;
  #pragma unroll
  for (int j = 0; j < 8; ++j) {
    float v = c.w00 * bf2f(s00[j]) + c.w01 * bf2f(s01[j])
            + c.w10 * bf2f(s10[j]) + c.w11 * bf2f(s11[j]);
    o[j] = f2bf(v);
  }
  return o;
}

// ---------------------------------------------------------------------------
// Kernel 0: pack weights into FRAGMENT-LINEAR bf16 streams (unchanged).
// ---------------------------------------------------------------------------
__global__ void prep_weights(const float* __restrict__ weight,
                             const float* __restrict__ offset_w,
                             const float* __restrict__ mask_w,
                             short* __restrict__ Bt2f,
                             short* __restrict__ Bt1f) {
  int idx = blockIdx.x * 256 + threadIdx.x;
  const int n2 = 9 * 4 * 16 * 512;          // 294912
  if (idx < n2) {
    int e = idx & 7, lane = (idx >> 3) & 63;
    int g = idx >> 9;
    int nl = g & 15, kq = (g >> 4) & 3, tap = g >> 6;
    int o = nl * 16 + (lane & 15);
    int c = kq * 32 + (lane >> 4) * 8 + e;
    Bt2f[idx] = f2bf(weight[(o * CIN + c) * 9 + tap]);
  } else {
    int j = idx - n2;
    if (j < 9 * 4 * 2 * 512) {              // 36864
      int e = j & 7, lane = (j >> 3) & 63;
      int g = j >> 9;
      int nl = g & 1, kq = (g >> 1) & 3, tap = g >> 3;
      int n = nl * 16 + (lane & 15);
      int c = kq * 32 + (lane >> 4) * 8 + e;
      float v = 0.f;
      if (n < 27)
        v = (n < 18) ? offset_w[(n * CIN + c) * 9 + tap]
                     : mask_w[((n - 18) * CIN + c) * 9 + tap];
      Bt1f[j] = f2bf(v);
    }
  }
}

// ---------------------------------------------------------------------------
// Kernel 0b: transpose x NCHW fp32 -> NHWC bf16 (unchanged).
// ---------------------------------------------------------------------------
__global__ __launch_bounds__(256, 8)
void transpose_x(const float* __restrict__ x, short* __restrict__ xt) {
  __shared__ short tile[64 * 130];
  const int tid = threadIdx.x;
  const int lane = tid & 63;
  const int wv = tid >> 6;
  const int p0 = blockIdx.x * 64;
  const int b = p0 / HW;
  const int hw0 = p0 % HW;
  const float* xb = x + (size_t)b * CIN * HW + hw0;

  #pragma unroll
  for (int i = 0; i < 32; ++i) {
    int c = wv + i * 4;
    tile[lane * 130 + c] = f2bf(xb[(size_t)c * HW + lane]);
  }
  __syncthreads();

  unsigned int* dst = (unsigned int*)(xt + ((size_t)b * HW + hw0) * 128);
  #pragma unroll
  for (int i = 0; i < 16; ++i) {
    int idx = i * 256 + tid;
    int px = idx >> 6, cw = idx & 63;
    unsigned int lo = (unsigned short)tile[px * 130 + 2 * cw];
    unsigned int hi = (unsigned short)tile[px * 130 + 2 * cw + 1];
    dst[idx] = lo | (hi << 16);
  }
}

// ---------------------------------------------------------------------------
// Kernel 1: offset+mask conv (unchanged).
// ---------------------------------------------------------------------------
__global__ __launch_bounds__(256, 4)
void offmask_kernel(const short* __restrict__ xt,
                    const short* __restrict__ Bt1f,
                    const float* __restrict__ offset_b,
                    const float* __restrict__ mask_b,
                    float* __restrict__ pmt) {
  const int tid  = threadIdx.x;
  const int lane = tid & 63;
  const int wv   = tid >> 6;
  const int q    = lane >> 4;
  const int m    = lane & 15;
  const int blk  = blockIdx.x;
  const int l    = (blk & 7) * BLK_PER_IMG + (blk >> 3);
  const int p0   = l * 64;
  const int b    = p0 / HW;
  const int p    = p0 + wv * 16 + m;
  const int hw   = p % HW;
  const int h    = hw / IW, w_ = hw % IW;
  const short* xtb = xt + (size_t)b * HW * 128;

  floatx4 acc0 = (floatx4){0.f, 0.f, 0.f, 0.f};
  floatx4 acc1 = (floatx4){0.f, 0.f, 0.f, 0.f};

  for (int tap = 0; tap < 9; ++tap) {
    const int kh = tap / 3, kw = tap % 3;
    const int iy = h + kh - 1, ix = w_ + kw - 1;
    const bool vald = (iy >= 0 && iy < IH && ix >= 0 && ix < IW);
    const size_t pbase = vald ? (size_t)(iy * IW + ix) * 128 : 0;

    short8 a[4], bb0[4], bb1[4];
    #pragma unroll
    for (int kq = 0; kq < 4; ++kq)
      a[kq] = *(const short8*)(xtb + pbase + kq * 32 + q * 8);
    #pragma unroll
    for (int kq = 0; kq < 4; ++kq) {
      bb0[kq] = *(const short8*)(Bt1f + (size_t)((tap * 4 + kq) * 2 + 0) * 512 + lane * 8);
      bb1[kq] = *(const short8*)(Bt1f + (size_t)((tap * 4 + kq) * 2 + 1) * 512 + lane * 8);
    }
    #pragma unroll
    for (int kq = 0; kq < 4; ++kq) {
      short8 av = a[kq];
      if (!vald) av = (short8){0, 0, 0, 0, 0, 0, 0, 0};
      acc0 = __builtin_amdgcn_mfma_f32_16x16x32_bf16(av, bb0[kq], acc0, 0, 0, 0);
      acc1 = __builtin_amdgcn_mfma_f32_16x16x32_bf16(av, bb1[kq], acc1, 0, 0, 0);
    }
  }

  #pragma unroll
  for (int nl = 0; nl < 2; ++nl) {
    floatx4 ac = nl ? acc1 : acc0;
    int ch = nl * 16 + m;
    if (ch < 18) {
      int tap = ch >> 1, plane = ch & 1;
      float cb = offset_b[ch];
      #pragma unroll
      for (int r = 0; r < 4; ++r) {
        int pp = p0 + wv * 16 + q * 4 + r;
        int hwp = pp % HW;
        float base = plane ? (float)(hwp % IW + tap % 3 - 1)
                           : (float)(hwp / IW + tap / 3 - 1);
        pmt[(size_t)(plane * 9 + tap) * NPIX + pp] = ac[r] + cb + base;
      }
    } else if (ch < 27) {
      int tap = ch - 18;
      float cb = mask_b[tap];
      #pragma unroll
      for (int r = 0; r < 4; ++r) {
        int pp = p0 + wv * 16 + q * 4 + r;
        float v = ac[r] + cb;
        pmt[(size_t)(18 + tap) * NPIX + pp] = 1.f / (1.f + expf(-v));
      }
    }
  }
}

// ---------------------------------------------------------------------------
// Kernel 2: fused sampling + deformable GEMM.
//  R2 restructure: per tap, VMEM issue order is
//   [bf01][g01][kq0][kq1][bf23][interp01][g23][kq2][kq3][interp23]
//  so no bf vmcnt wait ever drains a younger gather (vmcnt retires in issue
//  order): gathers get >=2 kq-steps of latency cover, and interp01's VALU
//  covers bf23's L2 latency.  LDS swizzle upgraded from ^(row&3) to
//  ^((row>>1)&7): with AST=136 (slot=(row+chunk)&7), this distributes each
//  wave access uniformly over all 8 bank slots (old swizzle preserved
//  row+chunk parity -> half the banks -> 2x serialization, 1.06e7 conflict
//  cycles/dispatch).
// ---------------------------------------------------------------------------
__global__ __launch_bounds__(256, 2)
void deform_main(const short* __restrict__ xt,
                 const short* __restrict__ Bt2f,
                 const float* __restrict__ pmt,
                 const float* __restrict__ bias,
                 float* __restrict__ out) {
  __shared__ short Ald[2][64 * AST];        // 34816 B

  const int tid  = threadIdx.x;
  const int lane = tid & 63;
  const int wv   = tid >> 6;
  const int q    = lane >> 4;
  const int m    = lane & 15;
  const int blk  = blockIdx.x;
  const int l    = (blk & 7) * BLK_PER_IMG + (blk >> 3);
  const int p0   = l * 64;
  const int b    = p0 / HW;
  const short* xtb = xt + (size_t)b * HW * 128;

  const int spx   = lane;                   // pixel this thread stages
  const int p_s   = p0 + spx;
  const int choff = wv * 32;                // channel window staged (shorts)
  const int wsw   = (spx >> 1) & 7;         // write-side XOR key (uniform slots)
  const int rsw   = (m >> 1) & 7;           // read-side XOR key
  short* const myrow0 = &Ald[0][spx * AST];
  short* const myrow1 = &Ald[1][spx * AST];

  floatx4 acc[4][4];
  #pragma unroll
  for (int i = 0; i < 4; ++i)
    #pragma unroll
    for (int j = 0; j < 4; ++j) acc[i][j] = (floatx4){0.f, 0.f, 0.f, 0.f};

  // ---- stage tap 0 ----
  {
    float py = pmt[p_s];
    float px = pmt[(size_t)9 * NPIX + p_s];
    float mk = pmt[(size_t)18 * NPIX + p_s];
    Corner c = corner_setup(py, px, mk, xtb, choff);
    #pragma unroll
    for (int i = 0; i < 4; ++i) {
      short8 s00 = *(const short8*)(c.r00 + i * 8);
      short8 s01 = *(const short8*)(c.r01 + i * 8);
      short8 s10 = *(const short8*)(c.r10 + i * 8);
      short8 s11 = *(const short8*)(c.r11 + i * 8);
      *(short8*)(myrow0 + ((wv * 4 + i) ^ wsw) * 8) = interp8(s00, s01, s10, s11, c);
    }
  }
  // preload pmt for tap 1
  float pyN = pmt[(size_t)1 * NPIX + p_s];
  float pxN = pmt[(size_t)10 * NPIX + p_s];
  float mkN = pmt[(size_t)19 * NPIX + p_s];
  __syncthreads();

  for (int tap = 0; tap < 9; ++tap) {
    const short* bufr = Ald[tap & 1];
    short* const roww = (tap & 1) ? myrow0 : myrow1;
    const bool nxt = (tap < 8);

    Corner c;
    if (nxt) c = corner_setup(pyN, pxN, mkN, xtb, choff);
    if (tap < 7) {
      pyN = pmt[(size_t)(tap + 2) * NPIX + p_s];
      pxN = pmt[(size_t)(tap + 11) * NPIX + p_s];
      mkN = pmt[(size_t)(tap + 20) * NPIX + p_s];
    }

    // ---- chunks 0,1: B-frags then gathers (gathers younger -> never drained)
    short8 bfA[4], bfB[4];
    #pragma unroll
    for (int nl = 0; nl < 4; ++nl) {
      bfA[nl] = *(const short8*)(Bt2f + (size_t)((tap * 4 + 0) * 16 + wv * 4 + nl) * 512 + lane * 8);
      bfB[nl] = *(const short8*)(Bt2f + (size_t)((tap * 4 + 1) * 16 + wv * 4 + nl) * 512 + lane * 8);
    }
    short8 gA0, gA1, gA2, gA3, gB0, gB1, gB2, gB3;
    if (nxt) {
      gA0 = *(const short8*)(c.r00 + 0);  gA1 = *(const short8*)(c.r01 + 0);
      gA2 = *(const short8*)(c.r10 + 0);  gA3 = *(const short8*)(c.r11 + 0);
      gB0 = *(const short8*)(c.r00 + 8);  gB1 = *(const short8*)(c.r01 + 8);
      gB2 = *(const short8*)(c.r10 + 8);  gB3 = *(const short8*)(c.r11 + 8);
    }
    // kq0
    {
      short8 af[4];
      #pragma unroll
      for (int mt = 0; mt < 4; ++mt)
        af[mt] = *(const short8*)(bufr + (mt * 16 + m) * AST + ((0 * 4 + q) ^ rsw) * 8);
      #pragma unroll
      for (int mt = 0; mt < 4; ++mt)
        #pragma unroll
        for (int nl = 0; nl < 4; ++nl)
          acc[mt][nl] = __builtin_amdgcn_mfma_f32_16x16x32_bf16(af[mt], bfA[nl], acc[mt][nl], 0, 0, 0);
    }
    // kq1
    {
      short8 af[4];
      #pragma unroll
      for (int mt = 0; mt < 4; ++mt)
        af[mt] = *(const short8*)(bufr + (mt * 16 + m) * AST + ((1 * 4 + q) ^ rsw) * 8);
      #pragma unroll
      for (int mt = 0; mt < 4; ++mt)
        #pragma unroll
        for (int nl = 0; nl < 4; ++nl)
          acc[mt][nl] = __builtin_amdgcn_mfma_f32_16x16x32_bf16(af[mt], bfB[nl], acc[mt][nl], 0, 0, 0);
    }
    // ---- chunks 2,3 B-frags in flight while interp01's VALU runs
    short8 bfC[4], bfD[4];
    #pragma unroll
    for (int nl = 0; nl < 4; ++nl) {
      bfC[nl] = *(const short8*)(Bt2f + (size_t)((tap * 4 + 2) * 16 + wv * 4 + nl) * 512 + lane * 8);
      bfD[nl] = *(const short8*)(Bt2f + (size_t)((tap * 4 + 3) * 16 + wv * 4 + nl) * 512 + lane * 8);
    }
    if (nxt) {
      *(short8*)(roww + ((wv * 4 + 0) ^ wsw) * 8) = interp8(gA0, gA1, gA2, gA3, c);
      *(short8*)(roww + ((wv * 4 + 1) ^ wsw) * 8) = interp8(gB0, gB1, gB2, gB3, c);
      // gathers chunks 2,3 (issued after interp01's waits -> full kq2+kq3 cover)
      gA0 = *(const short8*)(c.r00 + 16);  gA1 = *(const short8*)(c.r01 + 16);
      gA2 = *(const short8*)(c.r10 + 16);  gA3 = *(const short8*)(c.r11 + 16);
      gB0 = *(const short8*)(c.r00 + 24);  gB1 = *(const short8*)(c.r01 + 24);
      gB2 = *(const short8*)(c.r10 + 24);  gB3 = *(const short8*)(c.r11 + 24);
    }
    // kq2
    {
      short8 af[4];
      #pragma unroll
      for (int mt = 0; mt < 4; ++mt)
        af[mt] = *(const short8*)(bufr + (mt * 16 + m) * AST + ((2 * 4 + q) ^ rsw) * 8);
      #pragma unroll
      for (int mt = 0; mt < 4; ++mt)
        #pragma unroll
        for (int nl = 0; nl < 4; ++nl)
          acc[mt][nl] = __builtin_amdgcn_mfma_f32_16x16x32_bf16(af[mt], bfC[nl], acc[mt][nl], 0, 0, 0);
    }
    // kq3
    {
      short8 af[4];
      #pragma unroll
      for (int mt = 0; mt < 4; ++mt)
        af[mt] = *(const short8*)(bufr + (mt * 16 + m) * AST + ((3 * 4 + q) ^ rsw) * 8);
      #pragma unroll
      for (int mt = 0; mt < 4; ++mt)
        #pragma unroll
        for (int nl = 0; nl < 4; ++nl)
          acc[mt][nl] = __builtin_amdgcn_mfma_f32_16x16x32_bf16(af[mt], bfD[nl], acc[mt][nl], 0, 0, 0);
    }
    if (nxt) {
      *(short8*)(roww + ((wv * 4 + 2) ^ wsw) * 8) = interp8(gA0, gA1, gA2, gA3, c);
      *(short8*)(roww + ((wv * 4 + 3) ^ wsw) * 8) = interp8(gB0, gB1, gB2, gB3, c);
      __syncthreads();
    }
  }

  // ---- epilogue: direct stores.  D: row=q*4+r -> px mt*16+q*4+r, col=m ----
  const int hw0 = p0 % HW;
  #pragma unroll
  for (int nl = 0; nl < 4; ++nl) {
    const int o = wv * 64 + nl * 16 + m;
    const float bs = bias[o];
    float* op = out + (size_t)(b * COUT + o) * HW + hw0;
    #pragma unroll
    for (int mt = 0; mt < 4; ++mt) {
      floatx4 v = acc[mt][nl];
      v[0] += bs; v[1] += bs; v[2] += bs; v[3] += bs;
      *(floatx4*)(op + mt * 16 + q * 4) = v;
    }
  }
}

// ---------------------------------------------------------------------------
extern "C" void kernel_launch(void* const* d_in, const int* in_sizes, int n_in,
                              void* d_out, int out_size, void* d_ws, size_t ws_size,
                              hipStream_t stream) {
  const float* x        = (const float*)d_in[0];
  const float* offset_w = (const float*)d_in[1];
  const float* offset_b = (const float*)d_in[2];
  const float* mask_w   = (const float*)d_in[3];
  const float* mask_b   = (const float*)d_in[4];
  const float* weight   = (const float*)d_in[5];
  const float* bias     = (const float*)d_in[6];
  float* out = (float*)d_out;

  char* ws = (char*)d_ws;
  const size_t XT_BYTES  = (size_t)NPIX * 128 * 2;        // 18,874,368
  const size_t PMT_BYTES = (size_t)27 * NPIX * 4;         //  7,962,624
  const size_t BT2_BYTES = (size_t)9 * 4 * 16 * 512 * 2;  //    589,824
  short* xtp  = (short*)ws;
  float* pmt  = (float*)(ws + XT_BYTES);
  short* Bt2f = (short*)(ws + XT_BYTES + PMT_BYTES);
  short* Bt1f = (short*)(ws + XT_BYTES + PMT_BYTES + BT2_BYTES);

  prep_weights<<<dim3(1296), dim3(256), 0, stream>>>(weight, offset_w, mask_w, Bt2f, Bt1f);
  transpose_x<<<dim3(NPIX / 64), dim3(256), 0, stream>>>(x, xtp);
  offmask_kernel<<<dim3(NPIX / 64), dim3(256), 0, stream>>>(xtp, Bt1f, offset_b, mask_b, pmt);
  deform_main<<<dim3(NPIX / 64), dim3(256), 0, stream>>>(xtp, Bt2f, pmt, bias, out);
}

// Round 3
// 225.613 us; speedup vs baseline: 1.1454x; 1.1405x over previous
//
#include <hip/hip_runtime.h>

#define CIN 128
#define COUT 256
#define IH 96
#define IW 96
#define NB 8
#define HW (IH*IW)          // 9216
#define NPIX (NB*HW)        // 73728
#define AST 136             // LDS A-tile row stride (shorts), 17 x 16B chunks
#define BLK_PER_IMG (HW/64) // 144

typedef __attribute__((ext_vector_type(8))) short short8;
typedef __attribute__((ext_vector_type(4))) float floatx4;

static __device__ __forceinline__ short f2bf(float f) {
  unsigned int u = __builtin_bit_cast(unsigned int, f);
  u = u + 0x7fffu + ((u >> 16) & 1u);
  return (short)(u >> 16);
}
static __device__ __forceinline__ float bf2f(short s) {
  unsigned int u = ((unsigned int)(unsigned short)s) << 16;
  return __builtin_bit_cast(float, u);
}

struct Corner {
  float w00, w01, w10, w11;
  const short *r00, *r01, *r10, *r11;
};

// bilinear corner weights (validity & mask folded) + NHWC row pointers.
// choff: per-lane short offset folded into the row pointers.
static __device__ __forceinline__ Corner corner_setup(float py, float px, float mk,
                                                      const short* xtb, int choff) {
  Corner c;
  float y0f = floorf(py), x0f = floorf(px);
  float wy1 = py - y0f, wx1 = px - x0f;
  float wy0 = 1.f - wy1, wx0 = 1.f - wx1;
  bool vy0 = (y0f >= 0.f) && (y0f <= (float)(IH - 1));
  bool vy1 = (y0f + 1.f >= 0.f) && (y0f + 1.f <= (float)(IH - 1));
  bool vx0 = (x0f >= 0.f) && (x0f <= (float)(IW - 1));
  bool vx1 = (x0f + 1.f >= 0.f) && (x0f + 1.f <= (float)(IW - 1));
  int iy0 = min(max((int)y0f, 0), IH - 1);
  int iy1 = min(max((int)y0f + 1, 0), IH - 1);
  int ix0 = min(max((int)x0f, 0), IW - 1);
  int ix1 = min(max((int)x0f + 1, 0), IW - 1);
  c.w00 = wy0 * wx0 * mk * ((vy0 && vx0) ? 1.f : 0.f);
  c.w01 = wy0 * wx1 * mk * ((vy0 && vx1) ? 1.f : 0.f);
  c.w10 = wy1 * wx0 * mk * ((vy1 && vx0) ? 1.f : 0.f);
  c.w11 = wy1 * wx1 * mk * ((vy1 && vx1) ? 1.f : 0.f);
  c.r00 = xtb + (size_t)(iy0 * IW + ix0) * 128 + choff;
  c.r01 = xtb + (size_t)(iy0 * IW + ix1) * 128 + choff;
  c.r10 = xtb + (size_t)(iy1 * IW + ix0) * 128 + choff;
  c.r11 = xtb + (size_t)(iy1 * IW + ix1) * 128 + choff;
  return c;
}

static __device__ __forceinline__ short8 interp8(short8 s00, short8 s01,
                                                 short8 s10, short8 s11,
                                                 const Corner& c) {
  short8 o;
  #pragma unroll
  for (int j = 0; j < 8; ++j) {
    float v = c.w00 * bf2f(s00[j]) + c.w01 * bf2f(s01[j])
            + c.w10 * bf2f(s10[j]) + c.w11 * bf2f(s11[j]);
    o[j] = f2bf(v);
  }
  return o;
}

// ---------------------------------------------------------------------------
// Kernel 0: pack weights into FRAGMENT-LINEAR bf16 streams (unchanged).
// ---------------------------------------------------------------------------
__global__ void prep_weights(const float* __restrict__ weight,
                             const float* __restrict__ offset_w,
                             const float* __restrict__ mask_w,
                             short* __restrict__ Bt2f,
                             short* __restrict__ Bt1f) {
  int idx = blockIdx.x * 256 + threadIdx.x;
  const int n2 = 9 * 4 * 16 * 512;          // 294912
  if (idx < n2) {
    int e = idx & 7, lane = (idx >> 3) & 63;
    int g = idx >> 9;
    int nl = g & 15, kq = (g >> 4) & 3, tap = g >> 6;
    int o = nl * 16 + (lane & 15);
    int c = kq * 32 + (lane >> 4) * 8 + e;
    Bt2f[idx] = f2bf(weight[(o * CIN + c) * 9 + tap]);
  } else {
    int j = idx - n2;
    if (j < 9 * 4 * 2 * 512) {              // 36864
      int e = j & 7, lane = (j >> 3) & 63;
      int g = j >> 9;
      int nl = g & 1, kq = (g >> 1) & 3, tap = g >> 3;
      int n = nl * 16 + (lane & 15);
      int c = kq * 32 + (lane >> 4) * 8 + e;
      float v = 0.f;
      if (n < 27)
        v = (n < 18) ? offset_w[(n * CIN + c) * 9 + tap]
                     : mask_w[((n - 18) * CIN + c) * 9 + tap];
      Bt1f[j] = f2bf(v);
    }
  }
}

// ---------------------------------------------------------------------------
// Kernel 0b: transpose x NCHW fp32 -> NHWC bf16 (unchanged).
// ---------------------------------------------------------------------------
__global__ __launch_bounds__(256, 8)
void transpose_x(const float* __restrict__ x, short* __restrict__ xt) {
  __shared__ short tile[64 * 130];
  const int tid = threadIdx.x;
  const int lane = tid & 63;
  const int wv = tid >> 6;
  const int p0 = blockIdx.x * 64;
  const int b = p0 / HW;
  const int hw0 = p0 % HW;
  const float* xb = x + (size_t)b * CIN * HW + hw0;

  #pragma unroll
  for (int i = 0; i < 32; ++i) {
    int c = wv + i * 4;
    tile[lane * 130 + c] = f2bf(xb[(size_t)c * HW + lane]);
  }
  __syncthreads();

  unsigned int* dst = (unsigned int*)(xt + ((size_t)b * HW + hw0) * 128);
  #pragma unroll
  for (int i = 0; i < 16; ++i) {
    int idx = i * 256 + tid;
    int px = idx >> 6, cw = idx & 63;
    unsigned int lo = (unsigned short)tile[px * 130 + 2 * cw];
    unsigned int hi = (unsigned short)tile[px * 130 + 2 * cw + 1];
    dst[idx] = lo | (hi << 16);
  }
}

// ---------------------------------------------------------------------------
// Kernel 1: offset+mask conv (unchanged).
// ---------------------------------------------------------------------------
__global__ __launch_bounds__(256, 4)
void offmask_kernel(const short* __restrict__ xt,
                    const short* __restrict__ Bt1f,
                    const float* __restrict__ offset_b,
                    const float* __restrict__ mask_b,
                    float* __restrict__ pmt) {
  const int tid  = threadIdx.x;
  const int lane = tid & 63;
  const int wv   = tid >> 6;
  const int q    = lane >> 4;
  const int m    = lane & 15;
  const int blk  = blockIdx.x;
  const int l    = (blk & 7) * BLK_PER_IMG + (blk >> 3);
  const int p0   = l * 64;
  const int b    = p0 / HW;
  const int p    = p0 + wv * 16 + m;
  const int hw   = p % HW;
  const int h    = hw / IW, w_ = hw % IW;
  const short* xtb = xt + (size_t)b * HW * 128;

  floatx4 acc0 = (floatx4){0.f, 0.f, 0.f, 0.f};
  floatx4 acc1 = (floatx4){0.f, 0.f, 0.f, 0.f};

  for (int tap = 0; tap < 9; ++tap) {
    const int kh = tap / 3, kw = tap % 3;
    const int iy = h + kh - 1, ix = w_ + kw - 1;
    const bool vald = (iy >= 0 && iy < IH && ix >= 0 && ix < IW);
    const size_t pbase = vald ? (size_t)(iy * IW + ix) * 128 : 0;

    short8 a[4], bb0[4], bb1[4];
    #pragma unroll
    for (int kq = 0; kq < 4; ++kq)
      a[kq] = *(const short8*)(xtb + pbase + kq * 32 + q * 8);
    #pragma unroll
    for (int kq = 0; kq < 4; ++kq) {
      bb0[kq] = *(const short8*)(Bt1f + (size_t)((tap * 4 + kq) * 2 + 0) * 512 + lane * 8);
      bb1[kq] = *(const short8*)(Bt1f + (size_t)((tap * 4 + kq) * 2 + 1) * 512 + lane * 8);
    }
    #pragma unroll
    for (int kq = 0; kq < 4; ++kq) {
      short8 av = a[kq];
      if (!vald) av = (short8){0, 0, 0, 0, 0, 0, 0, 0};
      acc0 = __builtin_amdgcn_mfma_f32_16x16x32_bf16(av, bb0[kq], acc0, 0, 0, 0);
      acc1 = __builtin_amdgcn_mfma_f32_16x16x32_bf16(av, bb1[kq], acc1, 0, 0, 0);
    }
  }

  #pragma unroll
  for (int nl = 0; nl < 2; ++nl) {
    floatx4 ac = nl ? acc1 : acc0;
    int ch = nl * 16 + m;
    if (ch < 18) {
      int tap = ch >> 1, plane = ch & 1;
      float cb = offset_b[ch];
      #pragma unroll
      for (int r = 0; r < 4; ++r) {
        int pp = p0 + wv * 16 + q * 4 + r;
        int hwp = pp % HW;
        float base = plane ? (float)(hwp % IW + tap % 3 - 1)
                           : (float)(hwp / IW + tap / 3 - 1);
        pmt[(size_t)(plane * 9 + tap) * NPIX + pp] = ac[r] + cb + base;
      }
    } else if (ch < 27) {
      int tap = ch - 18;
      float cb = mask_b[tap];
      #pragma unroll
      for (int r = 0; r < 4; ++r) {
        int pp = p0 + wv * 16 + q * 4 + r;
        float v = ac[r] + cb;
        pmt[(size_t)(18 + tap) * NPIX + pp] = 1.f / (1.f + expf(-v));
      }
    }
  }
}

// ---------------------------------------------------------------------------
// Kernel 2: fused sampling + deformable GEMM — COOPERATIVE GATHER (R3).
//  Old gather: lane = pixel -> 64 lanes hit 64 distinct 128B lines per
//  instruction (~64 TA line-requests each); 42.5M line-requests total, the
//  hidden serial cost (R2 showed LDS conflicts & vmcnt order are off-path).
//  New mapping: lane = (pix_in_group<<3)|chunk; each instruction reads
//  8 pixels x one full 128B half-row, 8 lanes coalesced per line -> 8
//  line-requests per instruction (the minimum). Each wave handles 16 pixels
//  x all 128 channels (2 pixel-groups x 4 corners x 2 halves = 16 loads/tap).
//  LDS: row = pixel, chunk j=half*8+ck stored at slot half*8+(ck^((row>>1)&7))
//  -- same involution the MFMA-side reads already use (verified slot-uniform).
// ---------------------------------------------------------------------------
__global__ __launch_bounds__(256, 2)
void deform_main(const short* __restrict__ xt,
                 const short* __restrict__ Bt2f,
                 const float* __restrict__ pmt,
                 const float* __restrict__ bias,
                 float* __restrict__ out) {
  __shared__ short Ald[2][64 * AST];        // 34816 B

  const int tid  = threadIdx.x;
  const int lane = tid & 63;
  const int wv   = tid >> 6;
  const int q    = lane >> 4;
  const int m    = lane & 15;
  const int blk  = blockIdx.x;
  const int l    = (blk & 7) * BLK_PER_IMG + (blk >> 3);
  const int p0   = l * 64;
  const int b    = p0 / HW;
  const short* xtb = xt + (size_t)b * HW * 128;

  // cooperative-gather lane mapping: 8 lanes per pixel, ck = 16B chunk
  const int r8    = lane >> 3;              // pixel within group of 8
  const int ck    = lane & 7;               // chunk within 128B half-row
  const int ckoff = ck * 8;                 // shorts, folded into row ptrs
  const int row0  = wv * 16 + r8;           // pixel-group 0 row
  const int row1  = row0 + 8;               // pixel-group 1 row
  const int p_s0  = p0 + row0;
  const int p_s1  = p0 + row1;
  const int wk0   = (row0 >> 1) & 7;        // write swizzle keys
  const int wk1   = (row1 >> 1) & 7;
  const int wb0   = row0 * AST;
  const int wb1   = row1 * AST;
  const int rsw   = (m >> 1) & 7;           // MFMA-read swizzle key

  floatx4 acc[4][4];
  #pragma unroll
  for (int i = 0; i < 4; ++i)
    #pragma unroll
    for (int j = 0; j < 4; ++j) acc[i][j] = (floatx4){0.f, 0.f, 0.f, 0.f};

  // ---- stage tap 0 (cooperative) ----
  {
    float py0 = pmt[p_s0], px0 = pmt[(size_t)9 * NPIX + p_s0], mk0 = pmt[(size_t)18 * NPIX + p_s0];
    float py1 = pmt[p_s1], px1 = pmt[(size_t)9 * NPIX + p_s1], mk1 = pmt[(size_t)18 * NPIX + p_s1];
    Corner c0 = corner_setup(py0, px0, mk0, xtb, ckoff);
    Corner c1 = corner_setup(py1, px1, mk1, xtb, ckoff);
    short8 a0 = *(const short8*)(c0.r00),      a1 = *(const short8*)(c0.r01);
    short8 a2 = *(const short8*)(c0.r10),      a3 = *(const short8*)(c0.r11);
    short8 a4 = *(const short8*)(c0.r00 + 64), a5 = *(const short8*)(c0.r01 + 64);
    short8 a6 = *(const short8*)(c0.r10 + 64), a7 = *(const short8*)(c0.r11 + 64);
    short8 b0 = *(const short8*)(c1.r00),      b1 = *(const short8*)(c1.r01);
    short8 b2 = *(const short8*)(c1.r10),      b3 = *(const short8*)(c1.r11);
    short8 b4 = *(const short8*)(c1.r00 + 64), b5 = *(const short8*)(c1.r01 + 64);
    short8 b6 = *(const short8*)(c1.r10 + 64), b7 = *(const short8*)(c1.r11 + 64);
    *(short8*)(&Ald[0][wb0 + (ck ^ wk0) * 8])       = interp8(a0, a1, a2, a3, c0);
    *(short8*)(&Ald[0][wb0 + (8 + (ck ^ wk0)) * 8]) = interp8(a4, a5, a6, a7, c0);
    *(short8*)(&Ald[0][wb1 + (ck ^ wk1) * 8])       = interp8(b0, b1, b2, b3, c1);
    *(short8*)(&Ald[0][wb1 + (8 + (ck ^ wk1)) * 8]) = interp8(b4, b5, b6, b7, c1);
  }
  // preload pmt for tap 1 (both pixels)
  float pyN0 = pmt[(size_t)1 * NPIX + p_s0];
  float pxN0 = pmt[(size_t)10 * NPIX + p_s0];
  float mkN0 = pmt[(size_t)19 * NPIX + p_s0];
  float pyN1 = pmt[(size_t)1 * NPIX + p_s1];
  float pxN1 = pmt[(size_t)10 * NPIX + p_s1];
  float mkN1 = pmt[(size_t)19 * NPIX + p_s1];
  __syncthreads();

  for (int tap = 0; tap < 9; ++tap) {
    const short* bufr = Ald[tap & 1];
    short* const wbuf = Ald[(tap & 1) ^ 1];
    const bool nxt = (tap < 8);

    Corner c0, c1;
    if (nxt) {
      c0 = corner_setup(pyN0, pxN0, mkN0, xtb, ckoff);
      c1 = corner_setup(pyN1, pxN1, mkN1, xtb, ckoff);
    }
    if (tap < 7) {
      pyN0 = pmt[(size_t)(tap + 2) * NPIX + p_s0];
      pxN0 = pmt[(size_t)(tap + 11) * NPIX + p_s0];
      mkN0 = pmt[(size_t)(tap + 20) * NPIX + p_s0];
      pyN1 = pmt[(size_t)(tap + 2) * NPIX + p_s1];
      pxN1 = pmt[(size_t)(tap + 11) * NPIX + p_s1];
      mkN1 = pmt[(size_t)(tap + 20) * NPIX + p_s1];
    }

    // ---- B-frags kq0,kq1 + pixel-group-0 gathers in flight over kq0/kq1
    short8 bfA[4], bfB[4];
    #pragma unroll
    for (int nl = 0; nl < 4; ++nl) {
      bfA[nl] = *(const short8*)(Bt2f + (size_t)((tap * 4 + 0) * 16 + wv * 4 + nl) * 512 + lane * 8);
      bfB[nl] = *(const short8*)(Bt2f + (size_t)((tap * 4 + 1) * 16 + wv * 4 + nl) * 512 + lane * 8);
    }
    short8 g0, g1, g2, g3, g4, g5, g6, g7;
    if (nxt) {
      g0 = *(const short8*)(c0.r00);      g1 = *(const short8*)(c0.r01);
      g2 = *(const short8*)(c0.r10);      g3 = *(const short8*)(c0.r11);
      g4 = *(const short8*)(c0.r00 + 64); g5 = *(const short8*)(c0.r01 + 64);
      g6 = *(const short8*)(c0.r10 + 64); g7 = *(const short8*)(c0.r11 + 64);
    }
    // kq0
    {
      short8 af[4];
      #pragma unroll
      for (int mt = 0; mt < 4; ++mt)
        af[mt] = *(const short8*)(bufr + (mt * 16 + m) * AST + ((0 * 4 + q) ^ rsw) * 8);
      #pragma unroll
      for (int mt = 0; mt < 4; ++mt)
        #pragma unroll
        for (int nl = 0; nl < 4; ++nl)
          acc[mt][nl] = __builtin_amdgcn_mfma_f32_16x16x32_bf16(af[mt], bfA[nl], acc[mt][nl], 0, 0, 0);
    }
    // kq1
    {
      short8 af[4];
      #pragma unroll
      for (int mt = 0; mt < 4; ++mt)
        af[mt] = *(const short8*)(bufr + (mt * 16 + m) * AST + ((1 * 4 + q) ^ rsw) * 8);
      #pragma unroll
      for (int mt = 0; mt < 4; ++mt)
        #pragma unroll
        for (int nl = 0; nl < 4; ++nl)
          acc[mt][nl] = __builtin_amdgcn_mfma_f32_16x16x32_bf16(af[mt], bfB[nl], acc[mt][nl], 0, 0, 0);
    }
    // ---- B-frags kq2,kq3; interp pg0; pg1 gathers in flight over kq2/kq3
    short8 bfC[4], bfD[4];
    #pragma unroll
    for (int nl = 0; nl < 4; ++nl) {
      bfC[nl] = *(const short8*)(Bt2f + (size_t)((tap * 4 + 2) * 16 + wv * 4 + nl) * 512 + lane * 8);
      bfD[nl] = *(const short8*)(Bt2f + (size_t)((tap * 4 + 3) * 16 + wv * 4 + nl) * 512 + lane * 8);
    }
    if (nxt) {
      *(short8*)(&wbuf[wb0 + (ck ^ wk0) * 8])       = interp8(g0, g1, g2, g3, c0);
      *(short8*)(&wbuf[wb0 + (8 + (ck ^ wk0)) * 8]) = interp8(g4, g5, g6, g7, c0);
      g0 = *(const short8*)(c1.r00);      g1 = *(const short8*)(c1.r01);
      g2 = *(const short8*)(c1.r10);      g3 = *(const short8*)(c1.r11);
      g4 = *(const short8*)(c1.r00 + 64); g5 = *(const short8*)(c1.r01 + 64);
      g6 = *(const short8*)(c1.r10 + 64); g7 = *(const short8*)(c1.r11 + 64);
    }
    // kq2
    {
      short8 af[4];
      #pragma unroll
      for (int mt = 0; mt < 4; ++mt)
        af[mt] = *(const short8*)(bufr + (mt * 16 + m) * AST + ((2 * 4 + q) ^ rsw) * 8);
      #pragma unroll
      for (int mt = 0; mt < 4; ++mt)
        #pragma unroll
        for (int nl = 0; nl < 4; ++nl)
          acc[mt][nl] = __builtin_amdgcn_mfma_f32_16x16x32_bf16(af[mt], bfC[nl], acc[mt][nl], 0, 0, 0);
    }
    // kq3
    {
      short8 af[4];
      #pragma unroll
      for (int mt = 0; mt < 4; ++mt)
        af[mt] = *(const short8*)(bufr + (mt * 16 + m) * AST + ((3 * 4 + q) ^ rsw) * 8);
      #pragma unroll
      for (int mt = 0; mt < 4; ++mt)
        #pragma unroll
        for (int nl = 0; nl < 4; ++nl)
          acc[mt][nl] = __builtin_amdgcn_mfma_f32_16x16x32_bf16(af[mt], bfD[nl], acc[mt][nl], 0, 0, 0);
    }
    if (nxt) {
      *(short8*)(&wbuf[wb1 + (ck ^ wk1) * 8])       = interp8(g0, g1, g2, g3, c1);
      *(short8*)(&wbuf[wb1 + (8 + (ck ^ wk1)) * 8]) = interp8(g4, g5, g6, g7, c1);
      __syncthreads();
    }
  }

  // ---- epilogue: direct stores.  D: row=q*4+r -> px mt*16+q*4+r, col=m ----
  const int hw0 = p0 % HW;
  #pragma unroll
  for (int nl = 0; nl < 4; ++nl) {
    const int o = wv * 64 + nl * 16 + m;
    const float bs = bias[o];
    float* op = out + (size_t)(b * COUT + o) * HW + hw0;
    #pragma unroll
    for (int mt = 0; mt < 4; ++mt) {
      floatx4 v = acc[mt][nl];
      v[0] += bs; v[1] += bs; v[2] += bs; v[3] += bs;
      *(floatx4*)(op + mt * 16 + q * 4) = v;
    }
  }
}

// ---------------------------------------------------------------------------
extern "C" void kernel_launch(void* const* d_in, const int* in_sizes, int n_in,
                              void* d_out, int out_size, void* d_ws, size_t ws_size,
                              hipStream_t stream) {
  const float* x        = (const float*)d_in[0];
  const float* offset_w = (const float*)d_in[1];
  const float* offset_b = (const float*)d_in[2];
  const float* mask_w   = (const float*)d_in[3];
  const float* mask_b   = (const float*)d_in[4];
  const float* weight   = (const float*)d_in[5];
  const float* bias     = (const float*)d_in[6];
  float* out = (float*)d_out;

  char* ws = (char*)d_ws;
  const size_t XT_BYTES  = (size_t)NPIX * 128 * 2;        // 18,874,368
  const size_t PMT_BYTES = (size_t)27 * NPIX * 4;         //  7,962,624
  const size_t BT2_BYTES = (size_t)9 * 4 * 16 * 512 * 2;  //    589,824
  short* xtp  = (short*)ws;
  float* pmt  = (float*)(ws + XT_BYTES);
  short* Bt2f = (short*)(ws + XT_BYTES + PMT_BYTES);
  short* Bt1f = (short*)(ws + XT_BYTES + PMT_BYTES + BT2_BYTES);

  prep_weights<<<dim3(1296), dim3(256), 0, stream>>>(weight, offset_w, mask_w, Bt2f, Bt1f);
  transpose_x<<<dim3(NPIX / 64), dim3(256), 0, stream>>>(x, xtp);
  offmask_kernel<<<dim3(NPIX / 64), dim3(256), 0, stream>>>(xtp, Bt1f, offset_b, mask_b, pmt);
  deform_main<<<dim3(NPIX / 64), dim3(256), 0, stream>>>(xtp, Bt2f, pmt, bias, out);
}

// Round 4
// 221.357 us; speedup vs baseline: 1.1675x; 1.0192x over previous
//
#include <hip/hip_runtime.h>

#define CIN 128
#define COUT 256
#define IH 96
#define IW 96
#define NB 8
#define HW (IH*IW)          // 9216
#define NPIX (NB*HW)        // 73728
#define AST 136             // LDS A-tile row stride (shorts), 17 x 16B chunks
#define BLK_PER_IMG (HW/64) // 144

typedef __attribute__((ext_vector_type(8))) short short8;
typedef __attribute__((ext_vector_type(4))) float floatx4;

static __device__ __forceinline__ short f2bf(float f) {
  unsigned int u = __builtin_bit_cast(unsigned int, f);
  u = u + 0x7fffu + ((u >> 16) & 1u);
  return (short)(u >> 16);
}
static __device__ __forceinline__ float bf2f(short s) {
  unsigned int u = ((unsigned int)(unsigned short)s) << 16;
  return __builtin_bit_cast(float, u);
}

struct Corner {
  float w00, w01, w10, w11;
  const short *r00, *r01, *r10, *r11;
};

// bilinear corner weights (validity & mask folded) + NHWC row pointers.
// choff: per-lane short offset folded into the row pointers.
static __device__ __forceinline__ Corner corner_setup(float py, float px, float mk,
                                                      const short* xtb, int choff) {
  Corner c;
  float y0f = floorf(py), x0f = floorf(px);
  float wy1 = py - y0f, wx1 = px - x0f;
  float wy0 = 1.f - wy1, wx0 = 1.f - wx1;
  bool vy0 = (y0f >= 0.f) && (y0f <= (float)(IH - 1));
  bool vy1 = (y0f + 1.f >= 0.f) && (y0f + 1.f <= (float)(IH - 1));
  bool vx0 = (x0f >= 0.f) && (x0f <= (float)(IW - 1));
  bool vx1 = (x0f + 1.f >= 0.f) && (x0f + 1.f <= (float)(IW - 1));
  int iy0 = min(max((int)y0f, 0), IH - 1);
  int iy1 = min(max((int)y0f + 1, 0), IH - 1);
  int ix0 = min(max((int)x0f, 0), IW - 1);
  int ix1 = min(max((int)x0f + 1, 0), IW - 1);
  c.w00 = wy0 * wx0 * mk * ((vy0 && vx0) ? 1.f : 0.f);
  c.w01 = wy0 * wx1 * mk * ((vy0 && vx1) ? 1.f : 0.f);
  c.w10 = wy1 * wx0 * mk * ((vy1 && vx0) ? 1.f : 0.f);
  c.w11 = wy1 * wx1 * mk * ((vy1 && vx1) ? 1.f : 0.f);
  c.r00 = xtb + (size_t)(iy0 * IW + ix0) * 128 + choff;
  c.r01 = xtb + (size_t)(iy0 * IW + ix1) * 128 + choff;
  c.r10 = xtb + (size_t)(iy1 * IW + ix0) * 128 + choff;
  c.r11 = xtb + (size_t)(iy1 * IW + ix1) * 128 + choff;
  return c;
}

static __device__ __forceinline__ short8 interp8(short8 s00, short8 s01,
                                                 short8 s10, short8 s11,
                                                 const Corner& c) {
  short8 o;
  #pragma unroll
  for (int j = 0; j < 8; ++j) {
    float v = c.w00 * bf2f(s00[j]) + c.w01 * bf2f(s01[j])
            + c.w10 * bf2f(s10[j]) + c.w11 * bf2f(s11[j]);
    o[j] = f2bf(v);
  }
  return o;
}

// ---------------------------------------------------------------------------
// Kernel 0: pack weights into FRAGMENT-LINEAR bf16 streams (unchanged).
// ---------------------------------------------------------------------------
__global__ void prep_weights(const float* __restrict__ weight,
                             const float* __restrict__ offset_w,
                             const float* __restrict__ mask_w,
                             short* __restrict__ Bt2f,
                             short* __restrict__ Bt1f) {
  int idx = blockIdx.x * 256 + threadIdx.x;
  const int n2 = 9 * 4 * 16 * 512;          // 294912
  if (idx < n2) {
    int e = idx & 7, lane = (idx >> 3) & 63;
    int g = idx >> 9;
    int nl = g & 15, kq = (g >> 4) & 3, tap = g >> 6;
    int o = nl * 16 + (lane & 15);
    int c = kq * 32 + (lane >> 4) * 8 + e;
    Bt2f[idx] = f2bf(weight[(o * CIN + c) * 9 + tap]);
  } else {
    int j = idx - n2;
    if (j < 9 * 4 * 2 * 512) {              // 36864
      int e = j & 7, lane = (j >> 3) & 63;
      int g = j >> 9;
      int nl = g & 1, kq = (g >> 1) & 3, tap = g >> 3;
      int n = nl * 16 + (lane & 15);
      int c = kq * 32 + (lane >> 4) * 8 + e;
      float v = 0.f;
      if (n < 27)
        v = (n < 18) ? offset_w[(n * CIN + c) * 9 + tap]
                     : mask_w[((n - 18) * CIN + c) * 9 + tap];
      Bt1f[j] = f2bf(v);
    }
  }
}

// ---------------------------------------------------------------------------
// Kernel 0b: transpose x NCHW fp32 -> NHWC bf16 (unchanged).
// ---------------------------------------------------------------------------
__global__ __launch_bounds__(256, 8)
void transpose_x(const float* __restrict__ x, short* __restrict__ xt) {
  __shared__ short tile[64 * 130];
  const int tid = threadIdx.x;
  const int lane = tid & 63;
  const int wv = tid >> 6;
  const int p0 = blockIdx.x * 64;
  const int b = p0 / HW;
  const int hw0 = p0 % HW;
  const float* xb = x + (size_t)b * CIN * HW + hw0;

  #pragma unroll
  for (int i = 0; i < 32; ++i) {
    int c = wv + i * 4;
    tile[lane * 130 + c] = f2bf(xb[(size_t)c * HW + lane]);
  }
  __syncthreads();

  unsigned int* dst = (unsigned int*)(xt + ((size_t)b * HW + hw0) * 128);
  #pragma unroll
  for (int i = 0; i < 16; ++i) {
    int idx = i * 256 + tid;
    int px = idx >> 6, cw = idx & 63;
    unsigned int lo = (unsigned short)tile[px * 130 + 2 * cw];
    unsigned int hi = (unsigned short)tile[px * 130 + 2 * cw + 1];
    dst[idx] = lo | (hi << 16);
  }
}

// ---------------------------------------------------------------------------
// Kernel 1 (FUSED, R4): offset/mask conv runs as a PROLOGUE of the deform
// kernel.  Rationale: deform block l consumes pmt only for pixels
// [p0,p0+64) -- exactly what offmask block l produced.  The dependency is
// block-local, so the 8 MB pmt round-trip and the device-wide barrier
// between the two kernels were pure overhead (~85 us of latency-bound time
// that could not overlap with deform).  The 27 floats/pixel now go to LDS
// (stride 65 to avoid ds bank conflicts), and block i's deform phase
// overlaps block j's offmask phase across the grid.
// ---------------------------------------------------------------------------
__global__ __launch_bounds__(256, 3)
void deform_main(const short* __restrict__ xt,
                 const short* __restrict__ Bt2f,
                 const short* __restrict__ Bt1f,
                 const float* __restrict__ offset_b,
                 const float* __restrict__ mask_b,
                 const float* __restrict__ bias,
                 float* __restrict__ out) {
  __shared__ short Ald[2][64 * AST];        // 34816 B
  __shared__ float pmb[27 * 65];            //  7020 B  (py[9],px[9],mk[9] x 64 px)

  const int tid  = threadIdx.x;
  const int lane = tid & 63;
  const int wv   = tid >> 6;
  const int q    = lane >> 4;
  const int m    = lane & 15;
  const int blk  = blockIdx.x;
  const int l    = (blk & 7) * BLK_PER_IMG + (blk >> 3);
  const int p0   = l * 64;
  const int b    = p0 / HW;
  const short* xtb = xt + (size_t)b * HW * 128;

  // ===== PROLOGUE: offset/mask conv for this block's 64 pixels =====
  {
    const int p  = p0 + wv * 16 + m;
    const int hw = p % HW;
    const int h  = hw / IW, w_ = hw % IW;

    floatx4 acc0 = (floatx4){0.f, 0.f, 0.f, 0.f};
    floatx4 acc1 = (floatx4){0.f, 0.f, 0.f, 0.f};

    for (int tap = 0; tap < 9; ++tap) {
      const int kh = tap / 3, kw = tap % 3;
      const int iy = h + kh - 1, ix = w_ + kw - 1;
      const bool vald = (iy >= 0 && iy < IH && ix >= 0 && ix < IW);
      const size_t pbase = vald ? (size_t)(iy * IW + ix) * 128 : 0;

      short8 a[4], bb0[4], bb1[4];
      #pragma unroll
      for (int kq = 0; kq < 4; ++kq)
        a[kq] = *(const short8*)(xtb + pbase + kq * 32 + q * 8);
      #pragma unroll
      for (int kq = 0; kq < 4; ++kq) {
        bb0[kq] = *(const short8*)(Bt1f + (size_t)((tap * 4 + kq) * 2 + 0) * 512 + lane * 8);
        bb1[kq] = *(const short8*)(Bt1f + (size_t)((tap * 4 + kq) * 2 + 1) * 512 + lane * 8);
      }
      #pragma unroll
      for (int kq = 0; kq < 4; ++kq) {
        short8 av = a[kq];
        if (!vald) av = (short8){0, 0, 0, 0, 0, 0, 0, 0};
        acc0 = __builtin_amdgcn_mfma_f32_16x16x32_bf16(av, bb0[kq], acc0, 0, 0, 0);
        acc1 = __builtin_amdgcn_mfma_f32_16x16x32_bf16(av, bb1[kq], acc1, 0, 0, 0);
      }
    }

    #pragma unroll
    for (int nl = 0; nl < 2; ++nl) {
      floatx4 ac = nl ? acc1 : acc0;
      int ch = nl * 16 + m;
      if (ch < 18) {
        int tap = ch >> 1, plane = ch & 1;
        float cb = offset_b[ch];
        #pragma unroll
        for (int r = 0; r < 4; ++r) {
          int col = wv * 16 + q * 4 + r;
          int hwp = (p0 + col) % HW;
          float base = plane ? (float)(hwp % IW + tap % 3 - 1)
                             : (float)(hwp / IW + tap / 3 - 1);
          pmb[(plane * 9 + tap) * 65 + col] = ac[r] + cb + base;
        }
      } else if (ch < 27) {
        int tap = ch - 18;
        float cb = mask_b[tap];
        #pragma unroll
        for (int r = 0; r < 4; ++r) {
          int col = wv * 16 + q * 4 + r;
          float v = ac[r] + cb;
          pmb[(18 + tap) * 65 + col] = 1.f / (1.f + expf(-v));
        }
      }
    }
  }
  __syncthreads();

  // ===== MAIN: cooperative-gather sampling + deformable GEMM (R3) =====
  const int r8    = lane >> 3;              // pixel within group of 8
  const int ck    = lane & 7;               // chunk within 128B half-row
  const int ckoff = ck * 8;                 // shorts, folded into row ptrs
  const int row0  = wv * 16 + r8;           // pixel-group 0 row (local col)
  const int row1  = row0 + 8;               // pixel-group 1 row
  const int wk0   = (row0 >> 1) & 7;        // write swizzle keys
  const int wk1   = (row1 >> 1) & 7;
  const int wb0   = row0 * AST;
  const int wb1   = row1 * AST;
  const int rsw   = (m >> 1) & 7;           // MFMA-read swizzle key

  floatx4 acc[4][4];
  #pragma unroll
  for (int i = 0; i < 4; ++i)
    #pragma unroll
    for (int j = 0; j < 4; ++j) acc[i][j] = (floatx4){0.f, 0.f, 0.f, 0.f};

  // ---- stage tap 0 (cooperative) ----
  {
    float py0 = pmb[row0], px0 = pmb[9 * 65 + row0], mk0 = pmb[18 * 65 + row0];
    float py1 = pmb[row1], px1 = pmb[9 * 65 + row1], mk1 = pmb[18 * 65 + row1];
    Corner c0 = corner_setup(py0, px0, mk0, xtb, ckoff);
    Corner c1 = corner_setup(py1, px1, mk1, xtb, ckoff);
    short8 a0 = *(const short8*)(c0.r00),      a1 = *(const short8*)(c0.r01);
    short8 a2 = *(const short8*)(c0.r10),      a3 = *(const short8*)(c0.r11);
    short8 a4 = *(const short8*)(c0.r00 + 64), a5 = *(const short8*)(c0.r01 + 64);
    short8 a6 = *(const short8*)(c0.r10 + 64), a7 = *(const short8*)(c0.r11 + 64);
    short8 b0 = *(const short8*)(c1.r00),      b1 = *(const short8*)(c1.r01);
    short8 b2 = *(const short8*)(c1.r10),      b3 = *(const short8*)(c1.r11);
    short8 b4 = *(const short8*)(c1.r00 + 64), b5 = *(const short8*)(c1.r01 + 64);
    short8 b6 = *(const short8*)(c1.r10 + 64), b7 = *(const short8*)(c1.r11 + 64);
    *(short8*)(&Ald[0][wb0 + (ck ^ wk0) * 8])       = interp8(a0, a1, a2, a3, c0);
    *(short8*)(&Ald[0][wb0 + (8 + (ck ^ wk0)) * 8]) = interp8(a4, a5, a6, a7, c0);
    *(short8*)(&Ald[0][wb1 + (ck ^ wk1) * 8])       = interp8(b0, b1, b2, b3, c1);
    *(short8*)(&Ald[0][wb1 + (8 + (ck ^ wk1)) * 8]) = interp8(b4, b5, b6, b7, c1);
  }
  // preload pm for tap 1 (both pixels)
  float pyN0 = pmb[1 * 65 + row0];
  float pxN0 = pmb[10 * 65 + row0];
  float mkN0 = pmb[19 * 65 + row0];
  float pyN1 = pmb[1 * 65 + row1];
  float pxN1 = pmb[10 * 65 + row1];
  float mkN1 = pmb[19 * 65 + row1];
  __syncthreads();

  for (int tap = 0; tap < 9; ++tap) {
    const short* bufr = Ald[tap & 1];
    short* const wbuf = Ald[(tap & 1) ^ 1];
    const bool nxt = (tap < 8);

    Corner c0, c1;
    if (nxt) {
      c0 = corner_setup(pyN0, pxN0, mkN0, xtb, ckoff);
      c1 = corner_setup(pyN1, pxN1, mkN1, xtb, ckoff);
    }
    if (tap < 7) {
      pyN0 = pmb[(tap + 2) * 65 + row0];
      pxN0 = pmb[(tap + 11) * 65 + row0];
      mkN0 = pmb[(tap + 20) * 65 + row0];
      pyN1 = pmb[(tap + 2) * 65 + row1];
      pxN1 = pmb[(tap + 11) * 65 + row1];
      mkN1 = pmb[(tap + 20) * 65 + row1];
    }

    // ---- B-frags kq0,kq1 + pixel-group-0 gathers in flight over kq0/kq1
    short8 bfA[4], bfB[4];
    #pragma unroll
    for (int nl = 0; nl < 4; ++nl) {
      bfA[nl] = *(const short8*)(Bt2f + (size_t)((tap * 4 + 0) * 16 + wv * 4 + nl) * 512 + lane * 8);
      bfB[nl] = *(const short8*)(Bt2f + (size_t)((tap * 4 + 1) * 16 + wv * 4 + nl) * 512 + lane * 8);
    }
    short8 g0, g1, g2, g3, g4, g5, g6, g7;
    if (nxt) {
      g0 = *(const short8*)(c0.r00);      g1 = *(const short8*)(c0.r01);
      g2 = *(const short8*)(c0.r10);      g3 = *(const short8*)(c0.r11);
      g4 = *(const short8*)(c0.r00 + 64); g5 = *(const short8*)(c0.r01 + 64);
      g6 = *(const short8*)(c0.r10 + 64); g7 = *(const short8*)(c0.r11 + 64);
    }
    // kq0
    {
      short8 af[4];
      #pragma unroll
      for (int mt = 0; mt < 4; ++mt)
        af[mt] = *(const short8*)(bufr + (mt * 16 + m) * AST + ((0 * 4 + q) ^ rsw) * 8);
      #pragma unroll
      for (int mt = 0; mt < 4; ++mt)
        #pragma unroll
        for (int nl = 0; nl < 4; ++nl)
          acc[mt][nl] = __builtin_amdgcn_mfma_f32_16x16x32_bf16(af[mt], bfA[nl], acc[mt][nl], 0, 0, 0);
    }
    // kq1
    {
      short8 af[4];
      #pragma unroll
      for (int mt = 0; mt < 4; ++mt)
        af[mt] = *(const short8*)(bufr + (mt * 16 + m) * AST + ((1 * 4 + q) ^ rsw) * 8);
      #pragma unroll
      for (int mt = 0; mt < 4; ++mt)
        #pragma unroll
        for (int nl = 0; nl < 4; ++nl)
          acc[mt][nl] = __builtin_amdgcn_mfma_f32_16x16x32_bf16(af[mt], bfB[nl], acc[mt][nl], 0, 0, 0);
    }
    // ---- B-frags kq2,kq3; interp pg0; pg1 gathers in flight over kq2/kq3
    short8 bfC[4], bfD[4];
    #pragma unroll
    for (int nl = 0; nl < 4; ++nl) {
      bfC[nl] = *(const short8*)(Bt2f + (size_t)((tap * 4 + 2) * 16 + wv * 4 + nl) * 512 + lane * 8);
      bfD[nl] = *(const short8*)(Bt2f + (size_t)((tap * 4 + 3) * 16 + wv * 4 + nl) * 512 + lane * 8);
    }
    if (nxt) {
      *(short8*)(&wbuf[wb0 + (ck ^ wk0) * 8])       = interp8(g0, g1, g2, g3, c0);
      *(short8*)(&wbuf[wb0 + (8 + (ck ^ wk0)) * 8]) = interp8(g4, g5, g6, g7, c0);
      g0 = *(const short8*)(c1.r00);      g1 = *(const short8*)(c1.r01);
      g2 = *(const short8*)(c1.r10);      g3 = *(const short8*)(c1.r11);
      g4 = *(const short8*)(c1.r00 + 64); g5 = *(const short8*)(c1.r01 + 64);
      g6 = *(const short8*)(c1.r10 + 64); g7 = *(const short8*)(c1.r11 + 64);
    }
    // kq2
    {
      short8 af[4];
      #pragma unroll
      for (int mt = 0; mt < 4; ++mt)
        af[mt] = *(const short8*)(bufr + (mt * 16 + m) * AST + ((2 * 4 + q) ^ rsw) * 8);
      #pragma unroll
      for (int mt = 0; mt < 4; ++mt)
        #pragma unroll
        for (int nl = 0; nl < 4; ++nl)
          acc[mt][nl] = __builtin_amdgcn_mfma_f32_16x16x32_bf16(af[mt], bfC[nl], acc[mt][nl], 0, 0, 0);
    }
    // kq3
    {
      short8 af[4];
      #pragma unroll
      for (int mt = 0; mt < 4; ++mt)
        af[mt] = *(const short8*)(bufr + (mt * 16 + m) * AST + ((3 * 4 + q) ^ rsw) * 8);
      #pragma unroll
      for (int mt = 0; mt < 4; ++mt)
        #pragma unroll
        for (int nl = 0; nl < 4; ++nl)
          acc[mt][nl] = __builtin_amdgcn_mfma_f32_16x16x32_bf16(af[mt], bfD[nl], acc[mt][nl], 0, 0, 0);
    }
    if (nxt) {
      *(short8*)(&wbuf[wb1 + (ck ^ wk1) * 8])       = interp8(g0, g1, g2, g3, c1);
      *(short8*)(&wbuf[wb1 + (8 + (ck ^ wk1)) * 8]) = interp8(g4, g5, g6, g7, c1);
      __syncthreads();
    }
  }

  // ---- epilogue: direct stores.  D: row=q*4+r -> px mt*16+q*4+r, col=m ----
  const int hw0 = p0 % HW;
  #pragma unroll
  for (int nl = 0; nl < 4; ++nl) {
    const int o = wv * 64 + nl * 16 + m;
    const float bs = bias[o];
    float* op = out + (size_t)(b * COUT + o) * HW + hw0;
    #pragma unroll
    for (int mt = 0; mt < 4; ++mt) {
      floatx4 v = acc[mt][nl];
      v[0] += bs; v[1] += bs; v[2] += bs; v[3] += bs;
      *(floatx4*)(op + mt * 16 + q * 4) = v;
    }
  }
}

// ---------------------------------------------------------------------------
extern "C" void kernel_launch(void* const* d_in, const int* in_sizes, int n_in,
                              void* d_out, int out_size, void* d_ws, size_t ws_size,
                              hipStream_t stream) {
  const float* x        = (const float*)d_in[0];
  const float* offset_w = (const float*)d_in[1];
  const float* offset_b = (const float*)d_in[2];
  const float* mask_w   = (const float*)d_in[3];
  const float* mask_b   = (const float*)d_in[4];
  const float* weight   = (const float*)d_in[5];
  const float* bias     = (const float*)d_in[6];
  float* out = (float*)d_out;

  char* ws = (char*)d_ws;
  const size_t XT_BYTES  = (size_t)NPIX * 128 * 2;        // 18,874,368
  const size_t BT2_BYTES = (size_t)9 * 4 * 16 * 512 * 2;  //    589,824
  short* xtp  = (short*)ws;
  short* Bt2f = (short*)(ws + XT_BYTES);
  short* Bt1f = (short*)(ws + XT_BYTES + BT2_BYTES);

  prep_weights<<<dim3(1296), dim3(256), 0, stream>>>(weight, offset_w, mask_w, Bt2f, Bt1f);
  transpose_x<<<dim3(NPIX / 64), dim3(256), 0, stream>>>(x, xtp);
  deform_main<<<dim3(NPIX / 64), dim3(256), 0, stream>>>(xtp, Bt2f, Bt1f, offset_b, mask_b, bias, out);
}

// Round 5
// 217.638 us; speedup vs baseline: 1.1874x; 1.0171x over previous
//
#include <hip/hip_runtime.h>

#define CIN 128
#define COUT 256
#define IH 96
#define IW 96
#define NB 8
#define HW (IH*IW)          // 9216
#define NPIX (NB*HW)        // 73728
#define AST 136             // LDS A-tile row stride (shorts), 17 x 16B chunks
#define BLK_PER_IMG (HW/64) // 144
#define TBLK (NPIX/64)      // 1152 transpose blocks

typedef __attribute__((ext_vector_type(8))) short short8;
typedef __attribute__((ext_vector_type(4))) float floatx4;

static __device__ __forceinline__ short f2bf(float f) {
  unsigned int u = __builtin_bit_cast(unsigned int, f);
  u = u + 0x7fffu + ((u >> 16) & 1u);
  return (short)(u >> 16);
}
static __device__ __forceinline__ float bf2f(short s) {
  unsigned int u = ((unsigned int)(unsigned short)s) << 16;
  return __builtin_bit_cast(float, u);
}

struct Corner {
  float w00, w01, w10, w11;
  const short *r00, *r01, *r10, *r11;
};

// bilinear corner weights (validity & mask folded) + NHWC row pointers.
// choff: per-lane short offset folded into the row pointers.
static __device__ __forceinline__ Corner corner_setup(float py, float px, float mk,
                                                      const short* xtb, int choff) {
  Corner c;
  float y0f = floorf(py), x0f = floorf(px);
  float wy1 = py - y0f, wx1 = px - x0f;
  float wy0 = 1.f - wy1, wx0 = 1.f - wx1;
  bool vy0 = (y0f >= 0.f) && (y0f <= (float)(IH - 1));
  bool vy1 = (y0f + 1.f >= 0.f) && (y0f + 1.f <= (float)(IH - 1));
  bool vx0 = (x0f >= 0.f) && (x0f <= (float)(IW - 1));
  bool vx1 = (x0f + 1.f >= 0.f) && (x0f + 1.f <= (float)(IW - 1));
  int iy0 = min(max((int)y0f, 0), IH - 1);
  int iy1 = min(max((int)y0f + 1, 0), IH - 1);
  int ix0 = min(max((int)x0f, 0), IW - 1);
  int ix1 = min(max((int)x0f + 1, 0), IW - 1);
  c.w00 = wy0 * wx0 * mk * ((vy0 && vx0) ? 1.f : 0.f);
  c.w01 = wy0 * wx1 * mk * ((vy0 && vx1) ? 1.f : 0.f);
  c.w10 = wy1 * wx0 * mk * ((vy1 && vx0) ? 1.f : 0.f);
  c.w11 = wy1 * wx1 * mk * ((vy1 && vx1) ? 1.f : 0.f);
  c.r00 = xtb + (size_t)(iy0 * IW + ix0) * 128 + choff;
  c.r01 = xtb + (size_t)(iy0 * IW + ix1) * 128 + choff;
  c.r10 = xtb + (size_t)(iy1 * IW + ix0) * 128 + choff;
  c.r11 = xtb + (size_t)(iy1 * IW + ix1) * 128 + choff;
  return c;
}

static __device__ __forceinline__ short8 interp8(short8 s00, short8 s01,
                                                 short8 s10, short8 s11,
                                                 const Corner& c) {
  short8 o;
  #pragma unroll
  for (int j = 0; j < 8; ++j) {
    float v = c.w00 * bf2f(s00[j]) + c.w01 * bf2f(s01[j])
            + c.w10 * bf2f(s10[j]) + c.w11 * bf2f(s11[j]);
    o[j] = f2bf(v);
  }
  return o;
}

// ---------------------------------------------------------------------------
// Kernel 0 (R5, fused prep + transpose):
//  blocks [0,1152): transpose x NCHW fp32 -> NHWC bf16, VECTORIZED.
//   R4's version was 32 scalar global loads + 32 ds_write_b16 + 32 ds_read_u16
//   + 16 scalar stores per thread (~112 serialized ops) -> ~85 us for 9 us of
//   traffic (latency/issue-bound; Common-mistake #2).  Now: 8 float4 loads
//   (2 ch x 4 px each), 16 ds_write_b32 (2ch packed; banks = (4pq+k+cg)%32,
//   2-way max), ds_read_b32 pairs, 4 uint4 stores (1KB/wave contiguous).
//  blocks [1152,1476): weight packing (grid-strided, 4 elems/thread).
// ---------------------------------------------------------------------------
__global__ __launch_bounds__(256, 8)
void prep_and_transpose(const float* __restrict__ x, short* __restrict__ xt,
                        const float* __restrict__ weight,
                        const float* __restrict__ offset_w,
                        const float* __restrict__ mask_w,
                        short* __restrict__ Bt2f, short* __restrict__ Bt1f) {
  const int blk = blockIdx.x;
  const int tid = threadIdx.x;

  if (blk >= TBLK) {
    // ---- weight packing: 324 blocks x 256 threads x 4 elements ----
    const int n2 = 9 * 4 * 16 * 512;        // 294912
    int base = (blk - TBLK) * 1024 + tid;
    #pragma unroll
    for (int k = 0; k < 4; ++k) {
      int idx = base + k * 256;
      if (idx < n2) {
        int e = idx & 7, lane = (idx >> 3) & 63;
        int g = idx >> 9;
        int nl = g & 15, kq = (g >> 4) & 3, tap = g >> 6;
        int o = nl * 16 + (lane & 15);
        int c = kq * 32 + (lane >> 4) * 8 + e;
        Bt2f[idx] = f2bf(weight[(o * CIN + c) * 9 + tap]);
      } else {
        int j = idx - n2;                   // < 36864 by construction
        int e = j & 7, lane = (j >> 3) & 63;
        int g = j >> 9;
        int nl = g & 1, kq = (g >> 1) & 3, tap = g >> 3;
        int n = nl * 16 + (lane & 15);
        int c = kq * 32 + (lane >> 4) * 8 + e;
        float v = 0.f;
        if (n < 27)
          v = (n < 18) ? offset_w[(n * CIN + c) * 9 + tap]
                       : mask_w[((n - 18) * CIN + c) * 9 + tap];
        Bt1f[j] = f2bf(v);
      }
    }
    return;
  }

  // ---- transpose: 64 pixels x 128 channels ----
  __shared__ short tile[64 * 130];
  const int p0  = blk * 64;
  const int b   = p0 / HW;
  const int hw0 = p0 % HW;
  const float* xb = x + (size_t)b * CIN * HW + hw0;

  const int pq = tid & 15;                  // pixel quad (4*pq .. 4*pq+3)
  const int cg = tid >> 4;                  // channel-pair group (0..15)

  #pragma unroll
  for (int r = 0; r < 4; ++r) {
    const int c = r * 32 + cg * 2;
    float4 v0 = *(const float4*)(xb + (size_t)c * HW + 4 * pq);
    float4 v1 = *(const float4*)(xb + (size_t)(c + 1) * HW + 4 * pq);
    unsigned int d0 = (unsigned short)f2bf(v0.x) | ((unsigned int)(unsigned short)f2bf(v1.x) << 16);
    unsigned int d1 = (unsigned short)f2bf(v0.y) | ((unsigned int)(unsigned short)f2bf(v1.y) << 16);
    unsigned int d2 = (unsigned short)f2bf(v0.z) | ((unsigned int)(unsigned short)f2bf(v1.z) << 16);
    unsigned int d3 = (unsigned short)f2bf(v0.w) | ((unsigned int)(unsigned short)f2bf(v1.w) << 16);
    *(unsigned int*)(&tile[(4 * pq + 0) * 130 + c]) = d0;
    *(unsigned int*)(&tile[(4 * pq + 1) * 130 + c]) = d1;
    *(unsigned int*)(&tile[(4 * pq + 2) * 130 + c]) = d2;
    *(unsigned int*)(&tile[(4 * pq + 3) * 130 + c]) = d3;
  }
  __syncthreads();

  unsigned int* dst = (unsigned int*)(xt + ((size_t)b * HW + hw0) * 128);
  #pragma unroll
  for (int i = 0; i < 4; ++i) {
    int gidx = i * 1024 + tid * 4;          // dword index, 4 consecutive
    int px = gidx >> 6, cw0 = gidx & 63;
    uint4 w;
    w.x = *(const unsigned int*)(&tile[px * 130 + 2 * (cw0 + 0)]);
    w.y = *(const unsigned int*)(&tile[px * 130 + 2 * (cw0 + 1)]);
    w.z = *(const unsigned int*)(&tile[px * 130 + 2 * (cw0 + 2)]);
    w.w = *(const unsigned int*)(&tile[px * 130 + 2 * (cw0 + 3)]);
    *(uint4*)(dst + gidx) = w;
  }
}

// ---------------------------------------------------------------------------
// Kernel 1 (fused offmask prologue + deform GEMM) — unchanged from R4.
// ---------------------------------------------------------------------------
__global__ __launch_bounds__(256, 3)
void deform_main(const short* __restrict__ xt,
                 const short* __restrict__ Bt2f,
                 const short* __restrict__ Bt1f,
                 const float* __restrict__ offset_b,
                 const float* __restrict__ mask_b,
                 const float* __restrict__ bias,
                 float* __restrict__ out) {
  __shared__ short Ald[2][64 * AST];        // 34816 B
  __shared__ float pmb[27 * 65];            //  7020 B  (py[9],px[9],mk[9] x 64 px)

  const int tid  = threadIdx.x;
  const int lane = tid & 63;
  const int wv   = tid >> 6;
  const int q    = lane >> 4;
  const int m    = lane & 15;
  const int blk  = blockIdx.x;
  const int l    = (blk & 7) * BLK_PER_IMG + (blk >> 3);
  const int p0   = l * 64;
  const int b    = p0 / HW;
  const short* xtb = xt + (size_t)b * HW * 128;

  // ===== PROLOGUE: offset/mask conv for this block's 64 pixels =====
  {
    const int p  = p0 + wv * 16 + m;
    const int hw = p % HW;
    const int h  = hw / IW, w_ = hw % IW;

    floatx4 acc0 = (floatx4){0.f, 0.f, 0.f, 0.f};
    floatx4 acc1 = (floatx4){0.f, 0.f, 0.f, 0.f};

    for (int tap = 0; tap < 9; ++tap) {
      const int kh = tap / 3, kw = tap % 3;
      const int iy = h + kh - 1, ix = w_ + kw - 1;
      const bool vald = (iy >= 0 && iy < IH && ix >= 0 && ix < IW);
      const size_t pbase = vald ? (size_t)(iy * IW + ix) * 128 : 0;

      short8 a[4], bb0[4], bb1[4];
      #pragma unroll
      for (int kq = 0; kq < 4; ++kq)
        a[kq] = *(const short8*)(xtb + pbase + kq * 32 + q * 8);
      #pragma unroll
      for (int kq = 0; kq < 4; ++kq) {
        bb0[kq] = *(const short8*)(Bt1f + (size_t)((tap * 4 + kq) * 2 + 0) * 512 + lane * 8);
        bb1[kq] = *(const short8*)(Bt1f + (size_t)((tap * 4 + kq) * 2 + 1) * 512 + lane * 8);
      }
      #pragma unroll
      for (int kq = 0; kq < 4; ++kq) {
        short8 av = a[kq];
        if (!vald) av = (short8){0, 0, 0, 0, 0, 0, 0, 0};
        acc0 = __builtin_amdgcn_mfma_f32_16x16x32_bf16(av, bb0[kq], acc0, 0, 0, 0);
        acc1 = __builtin_amdgcn_mfma_f32_16x16x32_bf16(av, bb1[kq], acc1, 0, 0, 0);
      }
    }

    #pragma unroll
    for (int nl = 0; nl < 2; ++nl) {
      floatx4 ac = nl ? acc1 : acc0;
      int ch = nl * 16 + m;
      if (ch < 18) {
        int tap = ch >> 1, plane = ch & 1;
        float cb = offset_b[ch];
        #pragma unroll
        for (int r = 0; r < 4; ++r) {
          int col = wv * 16 + q * 4 + r;
          int hwp = (p0 + col) % HW;
          float base = plane ? (float)(hwp % IW + tap % 3 - 1)
                             : (float)(hwp / IW + tap / 3 - 1);
          pmb[(plane * 9 + tap) * 65 + col] = ac[r] + cb + base;
        }
      } else if (ch < 27) {
        int tap = ch - 18;
        float cb = mask_b[tap];
        #pragma unroll
        for (int r = 0; r < 4; ++r) {
          int col = wv * 16 + q * 4 + r;
          float v = ac[r] + cb;
          pmb[(18 + tap) * 65 + col] = 1.f / (1.f + expf(-v));
        }
      }
    }
  }
  __syncthreads();

  // ===== MAIN: cooperative-gather sampling + deformable GEMM (R3) =====
  const int r8    = lane >> 3;              // pixel within group of 8
  const int ck    = lane & 7;               // chunk within 128B half-row
  const int ckoff = ck * 8;                 // shorts, folded into row ptrs
  const int row0  = wv * 16 + r8;           // pixel-group 0 row (local col)
  const int row1  = row0 + 8;               // pixel-group 1 row
  const int wk0   = (row0 >> 1) & 7;        // write swizzle keys
  const int wk1   = (row1 >> 1) & 7;
  const int wb0   = row0 * AST;
  const int wb1   = row1 * AST;
  const int rsw   = (m >> 1) & 7;           // MFMA-read swizzle key

  floatx4 acc[4][4];
  #pragma unroll
  for (int i = 0; i < 4; ++i)
    #pragma unroll
    for (int j = 0; j < 4; ++j) acc[i][j] = (floatx4){0.f, 0.f, 0.f, 0.f};

  // ---- stage tap 0 (cooperative) ----
  {
    float py0 = pmb[row0], px0 = pmb[9 * 65 + row0], mk0 = pmb[18 * 65 + row0];
    float py1 = pmb[row1], px1 = pmb[9 * 65 + row1], mk1 = pmb[18 * 65 + row1];
    Corner c0 = corner_setup(py0, px0, mk0, xtb, ckoff);
    Corner c1 = corner_setup(py1, px1, mk1, xtb, ckoff);
    short8 a0 = *(const short8*)(c0.r00),      a1 = *(const short8*)(c0.r01);
    short8 a2 = *(const short8*)(c0.r10),      a3 = *(const short8*)(c0.r11);
    short8 a4 = *(const short8*)(c0.r00 + 64), a5 = *(const short8*)(c0.r01 + 64);
    short8 a6 = *(const short8*)(c0.r10 + 64), a7 = *(const short8*)(c0.r11 + 64);
    short8 b0 = *(const short8*)(c1.r00),      b1 = *(const short8*)(c1.r01);
    short8 b2 = *(const short8*)(c1.r10),      b3 = *(const short8*)(c1.r11);
    short8 b4 = *(const short8*)(c1.r00 + 64), b5 = *(const short8*)(c1.r01 + 64);
    short8 b6 = *(const short8*)(c1.r10 + 64), b7 = *(const short8*)(c1.r11 + 64);
    *(short8*)(&Ald[0][wb0 + (ck ^ wk0) * 8])       = interp8(a0, a1, a2, a3, c0);
    *(short8*)(&Ald[0][wb0 + (8 + (ck ^ wk0)) * 8]) = interp8(a4, a5, a6, a7, c0);
    *(short8*)(&Ald[0][wb1 + (ck ^ wk1) * 8])       = interp8(b0, b1, b2, b3, c1);
    *(short8*)(&Ald[0][wb1 + (8 + (ck ^ wk1)) * 8]) = interp8(b4, b5, b6, b7, c1);
  }
  // preload pm for tap 1 (both pixels)
  float pyN0 = pmb[1 * 65 + row0];
  float pxN0 = pmb[10 * 65 + row0];
  float mkN0 = pmb[19 * 65 + row0];
  float pyN1 = pmb[1 * 65 + row1];
  float pxN1 = pmb[10 * 65 + row1];
  float mkN1 = pmb[19 * 65 + row1];
  __syncthreads();

  for (int tap = 0; tap < 9; ++tap) {
    const short* bufr = Ald[tap & 1];
    short* const wbuf = Ald[(tap & 1) ^ 1];
    const bool nxt = (tap < 8);

    Corner c0, c1;
    if (nxt) {
      c0 = corner_setup(pyN0, pxN0, mkN0, xtb, ckoff);
      c1 = corner_setup(pyN1, pxN1, mkN1, xtb, ckoff);
    }
    if (tap < 7) {
      pyN0 = pmb[(tap + 2) * 65 + row0];
      pxN0 = pmb[(tap + 11) * 65 + row0];
      mkN0 = pmb[(tap + 20) * 65 + row0];
      pyN1 = pmb[(tap + 2) * 65 + row1];
      pxN1 = pmb[(tap + 11) * 65 + row1];
      mkN1 = pmb[(tap + 20) * 65 + row1];
    }

    // ---- B-frags kq0,kq1 + pixel-group-0 gathers in flight over kq0/kq1
    short8 bfA[4], bfB[4];
    #pragma unroll
    for (int nl = 0; nl < 4; ++nl) {
      bfA[nl] = *(const short8*)(Bt2f + (size_t)((tap * 4 + 0) * 16 + wv * 4 + nl) * 512 + lane * 8);
      bfB[nl] = *(const short8*)(Bt2f + (size_t)((tap * 4 + 1) * 16 + wv * 4 + nl) * 512 + lane * 8);
    }
    short8 g0, g1, g2, g3, g4, g5, g6, g7;
    if (nxt) {
      g0 = *(const short8*)(c0.r00);      g1 = *(const short8*)(c0.r01);
      g2 = *(const short8*)(c0.r10);      g3 = *(const short8*)(c0.r11);
      g4 = *(const short8*)(c0.r00 + 64); g5 = *(const short8*)(c0.r01 + 64);
      g6 = *(const short8*)(c0.r10 + 64); g7 = *(const short8*)(c0.r11 + 64);
    }
    // kq0
    {
      short8 af[4];
      #pragma unroll
      for (int mt = 0; mt < 4; ++mt)
        af[mt] = *(const short8*)(bufr + (mt * 16 + m) * AST + ((0 * 4 + q) ^ rsw) * 8);
      #pragma unroll
      for (int mt = 0; mt < 4; ++mt)
        #pragma unroll
        for (int nl = 0; nl < 4; ++nl)
          acc[mt][nl] = __builtin_amdgcn_mfma_f32_16x16x32_bf16(af[mt], bfA[nl], acc[mt][nl], 0, 0, 0);
    }
    // kq1
    {
      short8 af[4];
      #pragma unroll
      for (int mt = 0; mt < 4; ++mt)
        af[mt] = *(const short8*)(bufr + (mt * 16 + m) * AST + ((1 * 4 + q) ^ rsw) * 8);
      #pragma unroll
      for (int mt = 0; mt < 4; ++mt)
        #pragma unroll
        for (int nl = 0; nl < 4; ++nl)
          acc[mt][nl] = __builtin_amdgcn_mfma_f32_16x16x32_bf16(af[mt], bfB[nl], acc[mt][nl], 0, 0, 0);
    }
    // ---- B-frags kq2,kq3; interp pg0; pg1 gathers in flight over kq2/kq3
    short8 bfC[4], bfD[4];
    #pragma unroll
    for (int nl = 0; nl < 4; ++nl) {
      bfC[nl] = *(const short8*)(Bt2f + (size_t)((tap * 4 + 2) * 16 + wv * 4 + nl) * 512 + lane * 8);
      bfD[nl] = *(const short8*)(Bt2f + (size_t)((tap * 4 + 3) * 16 + wv * 4 + nl) * 512 + lane * 8);
    }
    if (nxt) {
      *(short8*)(&wbuf[wb0 + (ck ^ wk0) * 8])       = interp8(g0, g1, g2, g3, c0);
      *(short8*)(&wbuf[wb0 + (8 + (ck ^ wk0)) * 8]) = interp8(g4, g5, g6, g7, c0);
      g0 = *(const short8*)(c1.r00);      g1 = *(const short8*)(c1.r01);
      g2 = *(const short8*)(c1.r10);      g3 = *(const short8*)(c1.r11);
      g4 = *(const short8*)(c1.r00 + 64); g5 = *(const short8*)(c1.r01 + 64);
      g6 = *(const short8*)(c1.r10 + 64); g7 = *(const short8*)(c1.r11 + 64);
    }
    // kq2
    {
      short8 af[4];
      #pragma unroll
      for (int mt = 0; mt < 4; ++mt)
        af[mt] = *(const short8*)(bufr + (mt * 16 + m) * AST + ((2 * 4 + q) ^ rsw) * 8);
      #pragma unroll
      for (int mt = 0; mt < 4; ++mt)
        #pragma unroll
        for (int nl = 0; nl < 4; ++nl)
          acc[mt][nl] = __builtin_amdgcn_mfma_f32_16x16x32_bf16(af[mt], bfC[nl], acc[mt][nl], 0, 0, 0);
    }
    // kq3
    {
      short8 af[4];
      #pragma unroll
      for (int mt = 0; mt < 4; ++mt)
        af[mt] = *(const short8*)(bufr + (mt * 16 + m) * AST + ((3 * 4 + q) ^ rsw) * 8);
      #pragma unroll
      for (int mt = 0; mt < 4; ++mt)
        #pragma unroll
        for (int nl = 0; nl < 4; ++nl)
          acc[mt][nl] = __builtin_amdgcn_mfma_f32_16x16x32_bf16(af[mt], bfD[nl], acc[mt][nl], 0, 0, 0);
    }
    if (nxt) {
      *(short8*)(&wbuf[wb1 + (ck ^ wk1) * 8])       = interp8(g0, g1, g2, g3, c1);
      *(short8*)(&wbuf[wb1 + (8 + (ck ^ wk1)) * 8]) = interp8(g4, g5, g6, g7, c1);
      __syncthreads();
    }
  }

  // ---- epilogue: direct stores.  D: row=q*4+r -> px mt*16+q*4+r, col=m ----
  const int hw0 = p0 % HW;
  #pragma unroll
  for (int nl = 0; nl < 4; ++nl) {
    const int o = wv * 64 + nl * 16 + m;
    const float bs = bias[o];
    float* op = out + (size_t)(b * COUT + o) * HW + hw0;
    #pragma unroll
    for (int mt = 0; mt < 4; ++mt) {
      floatx4 v = acc[mt][nl];
      v[0] += bs; v[1] += bs; v[2] += bs; v[3] += bs;
      *(floatx4*)(op + mt * 16 + q * 4) = v;
    }
  }
}

// ---------------------------------------------------------------------------
extern "C" void kernel_launch(void* const* d_in, const int* in_sizes, int n_in,
                              void* d_out, int out_size, void* d_ws, size_t ws_size,
                              hipStream_t stream) {
  const float* x        = (const float*)d_in[0];
  const float* offset_w = (const float*)d_in[1];
  const float* offset_b = (const float*)d_in[2];
  const float* mask_w   = (const float*)d_in[3];
  const float* mask_b   = (const float*)d_in[4];
  const float* weight   = (const float*)d_in[5];
  const float* bias     = (const float*)d_in[6];
  float* out = (float*)d_out;

  char* ws = (char*)d_ws;
  const size_t XT_BYTES  = (size_t)NPIX * 128 * 2;        // 18,874,368
  const size_t BT2_BYTES = (size_t)9 * 4 * 16 * 512 * 2;  //    589,824
  short* xtp  = (short*)ws;
  short* Bt2f = (short*)(ws + XT_BYTES);
  short* Bt1f = (short*)(ws + XT_BYTES + BT2_BYTES);

  prep_and_transpose<<<dim3(TBLK + 324), dim3(256), 0, stream>>>(
      x, xtp, weight, offset_w, mask_w, Bt2f, Bt1f);
  deform_main<<<dim3(NPIX / 64), dim3(256), 0, stream>>>(
      xtp, Bt2f, Bt1f, offset_b, mask_b, bias, out);
}